// Round 12
// baseline (779.546 us; speedup 1.0000x reference)
//
#include <hip/hip_runtime.h>
#include <math.h>

#define NNODES 50000
#define NEDGES 800000
#define D 128
#define NEG_SLOPE 0.2f
#define BN_EPS 1e-5f
#define SCAN_THREADS 1024
#define WAVE_REGION 3328                      // 52 elems x 64 lanes
#define COUNTS_PAD (16 * WAVE_REGION)         // 53248 >= 50000
#define DEG_BINS 1024

typedef __attribute__((ext_vector_type(8))) unsigned short ushort8_t;
typedef __attribute__((ext_vector_type(8))) short bf16x8;
typedef __attribute__((ext_vector_type(4))) float f32x4;

// RNE float -> bf16
__device__ __forceinline__ unsigned short f2bf(float x) {
  unsigned u = __float_as_uint(x);
  u += 0x7fffu + ((u >> 16) & 1u);
  return (unsigned short)(u >> 16);
}
__device__ __forceinline__ float bf2f(unsigned short h) {
  return __uint_as_float((unsigned)h << 16);
}

// ============ CSR build (once per call) ====================================
// rank[e] = position of edge e among edges with the same dst (atomic order)
__global__ __launch_bounds__(256) void k_rank(const int* __restrict__ dst,
        int* __restrict__ counts, int* __restrict__ rank, int E) {
  int e = blockIdx.x * 256 + threadIdx.x;
  if (e < E) rank[e] = atomicAdd(&counts[dst[e]], 1);
}

// Single-WG coalesced scan: wave w owns contiguous region of 3328 counts.
__global__ __launch_bounds__(1024) void k_scan_all(const int* __restrict__ counts,
        int* __restrict__ row_ptr, int n) {
  __shared__ int wtot[16];
  int t = threadIdx.x;
  int lane = t & 63, w = t >> 6;
  int rb = w * WAVE_REGION;
  int tot = 0;
  for (int j = 0; j < 52; ++j) tot += counts[rb + j * 64 + lane];
#pragma unroll
  for (int d = 1; d < 64; d <<= 1) tot += __shfl_xor(tot, d);
  if (lane == 0) wtot[w] = tot;
  __syncthreads();
  int wbase = 0;
#pragma unroll
  for (int i = 0; i < 16; ++i) wbase += (i < w) ? wtot[i] : 0;
  int running = wbase;
  for (int j = 0; j < 52; ++j) {
    int idx = rb + j * 64 + lane;
    int v = counts[idx];
    int incl = v;
#pragma unroll
    for (int d = 1; d < 64; d <<= 1) {
      int u = __shfl_up(incl, d);
      if (lane >= d) incl += u;
    }
    if (idx < n) row_ptr[idx + 1] = running + incl;
    running += __shfl(incl, 63);
  }
  if (t == 0) row_ptr[0] = 0;
}

// atomic-free placement: slot = row_ptr[dst] + rank
__global__ __launch_bounds__(256) void k_place(const int* __restrict__ src,
        const int* __restrict__ dst, const int* __restrict__ rank,
        const int* __restrict__ row_ptr, int* __restrict__ col_src, int E) {
  int e = blockIdx.x * 256 + threadIdx.x;
  if (e >= E) return;
  col_src[row_ptr[dst[e]] + rank[e]] = src[e];
}

// ---- degree counting-sort: node_order groups similar-degree nodes so the
// 4 nodes sharing a wave in k_agg have matched loop counts -----------------
__global__ __launch_bounds__(256) void k_deg_hist(const int* __restrict__ row_ptr,
        int* __restrict__ dhist, int n) {
  int i = blockIdx.x * 256 + threadIdx.x;
  if (i >= n) return;
  int d = row_ptr[i + 1] - row_ptr[i];
  if (d > DEG_BINS - 1) d = DEG_BINS - 1;
  atomicAdd(&dhist[d], 1);
}

__global__ __launch_bounds__(1024) void k_deg_scan(const int* __restrict__ dhist,
        int* __restrict__ dcur) {
  __shared__ int lds[DEG_BINS];
  int t = threadIdx.x;
  int v = dhist[t];
  lds[t] = v;
  __syncthreads();
  for (int off = 1; off < DEG_BINS; off <<= 1) {
    int u = (t >= off) ? lds[t - off] : 0;
    __syncthreads();
    lds[t] += u;
    __syncthreads();
  }
  dcur[t] = lds[t] - v;   // exclusive
}

__global__ __launch_bounds__(256) void k_deg_place(const int* __restrict__ row_ptr,
        int* __restrict__ dcur, int* __restrict__ node_order, int n) {
  int i = blockIdx.x * 256 + threadIdx.x;
  if (i >= n) return;
  int d = row_ptr[i + 1] - row_ptr[i];
  if (d > DEG_BINS - 1) d = DEG_BINS - 1;
  int pos = atomicAdd(&dcur[d], 1);
  node_order[pos] = i;
}

// ============ one-time converts ============================================

__global__ __launch_bounds__(256) void k_cvt_x(const float* __restrict__ x,
        unsigned short* __restrict__ xb, int total8) {
  int i = blockIdx.x * 256 + threadIdx.x;
  if (i >= total8) return;
  float4 a = ((const float4*)x)[2 * i];
  float4 b = ((const float4*)x)[2 * i + 1];
  uint4 pk;
  pk.x = (unsigned)f2bf(a.x) | ((unsigned)f2bf(a.y) << 16);
  pk.y = (unsigned)f2bf(a.z) | ((unsigned)f2bf(a.w) << 16);
  pk.z = (unsigned)f2bf(b.x) | ((unsigned)f2bf(b.y) << 16);
  pk.w = (unsigned)f2bf(b.z) | ((unsigned)f2bf(b.w) << 16);
  ((uint4*)xb)[i] = pk;
}

// W[l,s][k][col] f32 -> wt[(2l+s)][col][k] bf16 (transposed, K-contiguous)
__global__ void k_cvt_w(const float* __restrict__ Wl, const float* __restrict__ Wr,
        unsigned short* __restrict__ wt) {
  int ls = blockIdx.x;           // 0..5 = layer*2 + side
  int l = ls >> 1, s = ls & 1;
  const float* W = (s ? Wr : Wl) + l * D * D;
  unsigned short* o = wt + ls * D * D;
  for (int it = 0; it < 64; ++it) {
    int idx = it * 256 + threadIdx.x;
    int k = idx >> 7, c = idx & 127;
    o[c * D + k] = f2bf(W[idx]);
  }
}

// ============ GEMM: bf16 MFMA 16x16x32 =====================================
__global__ __launch_bounds__(256) void k_gemm(const unsigned short* __restrict__ xb,
        const unsigned short* __restrict__ wt,   // this layer: [2][128 col][128 k]
        unsigned short* __restrict__ xlb, unsigned short* __restrict__ xrb, int n) {
  __shared__ unsigned short xs[128 * 128];   // 32 KB
  const int t = threadIdx.x;
  const int row0 = blockIdx.x * 128;
  const unsigned short* __restrict__ W = wt + (size_t)blockIdx.y * (D * D);
  unsigned short* __restrict__ outp = blockIdx.y ? xrb : xlb;

#pragma unroll
  for (int i = 0; i < 8; ++i) {
    int ci = i * 256 + t;          // 16B-chunk index 0..2047
    int lr = ci >> 4, p = ci & 15;
    int grow = row0 + lr;
    if (grow >= n) grow = n - 1;   // clamped rows are never stored
    int gp = p ^ (lr & 7);
    uint4 v = *(const uint4*)(xb + (size_t)grow * D + gp * 8);
    *(uint4*)((char*)xs + ci * 16) = v;
  }
  __syncthreads();

  const int lane = t & 63, wv = t >> 6;
  const int colg = lane & 15, kg = lane >> 4;

  f32x4 acc[2][8];
#pragma unroll
  for (int rr = 0; rr < 2; ++rr)
#pragma unroll
    for (int cc = 0; cc < 8; ++cc) acc[rr][cc] = (f32x4)(0.f);

#pragma unroll
  for (int ks = 0; ks < 4; ++ks) {
    bf16x8 a[2], b[8];
#pragma unroll
    for (int rr = 0; rr < 2; ++rr) {
      int lr = wv * 32 + rr * 16 + colg;
      int byte = (lr * 256 + ks * 64 + kg * 16) ^ ((lr & 7) << 4);
      a[rr] = *(const bf16x8*)((const char*)xs + byte);
    }
#pragma unroll
    for (int cc = 0; cc < 8; ++cc) {
      int col = cc * 16 + colg;
      b[cc] = *(const bf16x8*)(W + (size_t)col * D + ks * 32 + kg * 8);
    }
#pragma unroll
    for (int rr = 0; rr < 2; ++rr)
#pragma unroll
      for (int cc = 0; cc < 8; ++cc)
        acc[rr][cc] = __builtin_amdgcn_mfma_f32_16x16x32_bf16(a[rr], b[cc], acc[rr][cc], 0, 0, 0);
  }

#pragma unroll
  for (int rr = 0; rr < 2; ++rr) {
    int rbase = row0 + wv * 32 + rr * 16 + kg * 4;
#pragma unroll
    for (int cc = 0; cc < 8; ++cc) {
      int col = cc * 16 + colg;
      f32x4 v = acc[rr][cc];
#pragma unroll
      for (int r = 0; r < 4; ++r) {
        int grow = rbase + r;
        if (grow < n) outp[(size_t)grow * D + col] = f2bf(v[r]);
      }
    }
  }
}

// ============ fused score + online-softmax + aggregate =====================
// 16 lanes per node (degree-sorted order), batch-4 gather pipelining.

__device__ __forceinline__ void agg_step(ushort8_t hv, const float* xrv,
        const float* atv, float& m, float& den, float* ac) {
  float v[8];
#pragma unroll
  for (int j = 0; j < 8; ++j) v[j] = bf2f(hv[j]);
  float p = 0.f;
#pragma unroll
  for (int j = 0; j < 8; ++j) {
    float tt = v[j] + xrv[j];
    tt = tt > 0.f ? tt : NEG_SLOPE * tt;
    p += tt * atv[j];
  }
  p += __shfl_xor(p, 1);
  p += __shfl_xor(p, 2);
  p += __shfl_xor(p, 4);
  p += __shfl_xor(p, 8);
  if (p > m) {
    float sc = __expf(m - p);
    den *= sc;
#pragma unroll
    for (int j = 0; j < 8; ++j) ac[j] *= sc;
    m = p;
  }
  float a = __expf(p - m);
  den += a;
#pragma unroll
  for (int j = 0; j < 8; ++j) ac[j] += a * v[j];
}

__global__ __launch_bounds__(256) void k_agg(const unsigned short* __restrict__ xlb,
        const unsigned short* __restrict__ xrb, const int* __restrict__ col_src,
        const int* __restrict__ row_ptr, const int* __restrict__ node_order,
        const float* __restrict__ att, float* __restrict__ out, int n) {
  int g = blockIdx.x * 16 + (threadIdx.x >> 4);
  if (g >= n) return;
  int node = node_order[g];
  int lane = threadIdx.x & 15;
  int ro = lane * 2;
  ushort8_t hr = ((const ushort8_t*)(xrb + (size_t)node * D))[lane];
  float xrv[8];
#pragma unroll
  for (int j = 0; j < 8; ++j) xrv[j] = bf2f(hr[j]);
  float4 at0 = ((const float4*)att)[ro];
  float4 at1 = ((const float4*)att)[ro + 1];
  float atv[8] = {at0.x, at0.y, at0.z, at0.w, at1.x, at1.y, at1.z, at1.w};

  int k0 = row_ptr[node], k1 = row_ptr[node + 1];
  float m = -1e30f, den = 0.f;
  float ac[8];
#pragma unroll
  for (int j = 0; j < 8; ++j) ac[j] = 0.f;

  const ushort8_t* xl8 = (const ushort8_t*)xlb;
  int k = k0;
  for (; k + 4 <= k1; k += 4) {
    int s0 = col_src[k], s1 = col_src[k + 1], s2 = col_src[k + 2], s3 = col_src[k + 3];
    ushort8_t h0 = xl8[(size_t)s0 * 16 + lane];
    ushort8_t h1 = xl8[(size_t)s1 * 16 + lane];
    ushort8_t h2 = xl8[(size_t)s2 * 16 + lane];
    ushort8_t h3 = xl8[(size_t)s3 * 16 + lane];
    agg_step(h0, xrv, atv, m, den, ac);
    agg_step(h1, xrv, atv, m, den, ac);
    agg_step(h2, xrv, atv, m, den, ac);
    agg_step(h3, xrv, atv, m, den, ac);
  }
  for (; k < k1; ++k) {
    int s = col_src[k];
    ushort8_t h = xl8[(size_t)s * 16 + lane];
    agg_step(h, xrv, atv, m, den, ac);
  }

  float inv = 1.f / (den + 1e-16f);
  float4* o4 = (float4*)out;
  o4[(size_t)node * 32 + ro]     = make_float4(ac[0] * inv, ac[1] * inv, ac[2] * inv, ac[3] * inv);
  o4[(size_t)node * 32 + ro + 1] = make_float4(ac[4] * inv, ac[5] * inv, ac[6] * inv, ac[7] * inv);
}

// ============ BatchNorm + GELU =============================================

__global__ __launch_bounds__(256) void k_bn_stats(const float* __restrict__ agg,
        float* __restrict__ sums, int n) {
  int c = threadIdx.x & 127;
  int half = threadIdx.x >> 7;
  float s = 0.f, s2 = 0.f;
  for (int r = blockIdx.x * 2 + half; r < n; r += gridDim.x * 2) {
    float v = agg[(size_t)r * D + c];
    s += v;
    s2 += v * v;
  }
  atomicAdd(&sums[c], s);
  atomicAdd(&sums[D + c], s2);
}

__global__ void k_bn_fin(const float* __restrict__ sums, const float* __restrict__ gamma,
        const float* __restrict__ beta, float* __restrict__ ss, float inv_n) {
  int c = threadIdx.x;
  float mu = sums[c] * inv_n;
  float var = sums[D + c] * inv_n - mu * mu;
  float rs = rsqrtf(var + BN_EPS);
  float sc = gamma[c] * rs;
  ss[c] = sc;
  ss[D + c] = beta[c] - mu * sc;
}

// writes f32 result AND bf16 mirror (next layer's GEMM input)
__global__ __launch_bounds__(256) void k_bn_apply(const float* __restrict__ agg,
        const float* __restrict__ ss, float* __restrict__ xo,
        unsigned short* __restrict__ xbo, int total4) {
  int i = blockIdx.x * 256 + threadIdx.x;
  if (i >= total4) return;
  float4 v = ((const float4*)agg)[i];
  int c4 = i & (D / 4 - 1);
  float4 sc = ((const float4*)ss)[c4];
  float4 sh = ((const float4*)ss)[D / 4 + c4];
  float y0 = sc.x * v.x + sh.x;
  float y1 = sc.y * v.y + sh.y;
  float y2 = sc.z * v.z + sh.z;
  float y3 = sc.w * v.w + sh.w;
  float4 g;
  g.x = 0.5f * y0 * (1.f + erff(y0 * 0.70710678118654752f));
  g.y = 0.5f * y1 * (1.f + erff(y1 * 0.70710678118654752f));
  g.z = 0.5f * y2 * (1.f + erff(y2 * 0.70710678118654752f));
  g.w = 0.5f * y3 * (1.f + erff(y3 * 0.70710678118654752f));
  ((float4*)xo)[i] = g;
  uint2 pk;
  pk.x = (unsigned)f2bf(g.x) | ((unsigned)f2bf(g.y) << 16);
  pk.y = (unsigned)f2bf(g.z) | ((unsigned)f2bf(g.w) << 16);
  ((uint2*)xbo)[i] = pk;
}

// ===========================================================================

extern "C" void kernel_launch(void* const* d_in, const int* in_sizes, int n_in,
                              void* d_out, int out_size, void* d_ws, size_t ws_size,
                              hipStream_t stream) {
  const float* x0    = (const float*)d_in[0];
  const int*   ei    = (const int*)d_in[1];
  const float* Wl    = (const float*)d_in[2];
  const float* Wr    = (const float*)d_in[3];
  const float* att   = (const float*)d_in[4];
  // d_in[5] = bias: cancelled exactly by BatchNorm mean-subtraction; unused.
  const float* gamma = (const float*)d_in[6];
  const float* beta  = (const float*)d_in[7];
  float* out = (float*)d_out;

  float* ws = (float*)d_ws;
  unsigned short* xb  = (unsigned short*)ws;              // [N][128] bf16
  unsigned short* xlb = (unsigned short*)(ws + 3200000);  // [N][128] bf16
  unsigned short* xrb = (unsigned short*)(ws + 6400000);  // [N][128] bf16
  int*   col_src    = (int*)(ws + 9600000);       //   800,000
  int*   rank       = (int*)(ws + 10400000);      //   800,000
  int*   row_ptr    = (int*)(ws + 11200000);      //    50,001
  int*   counts     = (int*)(ws + 11250004);      // COUNTS_PAD (53,248)
  int*   node_order = (int*)(ws + 11303252);      //    50,000
  int*   dhist      = (int*)(ws + 11353252);      //     1,024
  int*   dcur       = (int*)(ws + 11354276);      //     1,024
  float* sums       = ws + 11355300;              //       256
  float* ss         = ws + 11355556;              //       256
  unsigned short* wt = (unsigned short*)(ws + 11355812);  // [3][2][128][128] bf16

  const int* src = ei;
  const int* dst = ei + NEDGES;

  // ---- one-time: CSR build + degree sort + converts ----
  hipMemsetAsync(counts, 0, COUNTS_PAD * sizeof(int), stream);
  hipMemsetAsync(dhist, 0, DEG_BINS * sizeof(int), stream);
  k_rank<<<(NEDGES + 255) / 256, 256, 0, stream>>>(dst, counts, rank, NEDGES);
  k_scan_all<<<1, SCAN_THREADS, 0, stream>>>(counts, row_ptr, NNODES);
  k_place<<<(NEDGES + 255) / 256, 256, 0, stream>>>(src, dst, rank, row_ptr, col_src, NEDGES);
  k_deg_hist<<<(NNODES + 255) / 256, 256, 0, stream>>>(row_ptr, dhist, NNODES);
  k_deg_scan<<<1, DEG_BINS, 0, stream>>>(dhist, dcur);
  k_deg_place<<<(NNODES + 255) / 256, 256, 0, stream>>>(row_ptr, dcur, node_order, NNODES);
  k_cvt_w<<<6, 256, 0, stream>>>(Wl, Wr, wt);
  k_cvt_x<<<(NNODES * (D / 8) + 255) / 256, 256, 0, stream>>>(x0, xb, NNODES * (D / 8));

  dim3 ggrid((NNODES + 127) / 128, 2);

  for (int l = 0; l < 3; ++l) {
    k_gemm<<<ggrid, 256, 0, stream>>>(xb, wt + (size_t)l * 2 * D * D, xlb, xrb, NNODES);
    hipMemsetAsync(sums, 0, 2 * D * sizeof(float), stream);

    // d_out is dead as an input after k_gemm -> safe to overwrite with agg.
    k_agg<<<(NNODES + 15) / 16, 256, 0, stream>>>(xlb, xrb, col_src, row_ptr,
                                                  node_order, att + l * D, out, NNODES);

    k_bn_stats<<<512, 256, 0, stream>>>(out, sums, NNODES);
    k_bn_fin<<<1, D, 0, stream>>>(sums, gamma + l * D, beta + l * D, ss, 1.0f / NNODES);
    k_bn_apply<<<(NNODES * (D / 4) + 255) / 256, 256, 0, stream>>>(out, ss, out, xb,
                                                                   NNODES * (D / 4));
  }
}

// Round 13
// 509.471 us; speedup vs baseline: 1.5301x; 1.5301x over previous
//
#include <hip/hip_runtime.h>
#include <math.h>

#define NNODES 50000
#define NEDGES 800000
#define D 128
#define NEG_SLOPE 0.2f
#define BN_EPS 1e-5f
#define SCAN_THREADS 1024
#define WAVE_REGION 3328                      // 52 elems x 64 lanes
#define COUNTS_PAD (16 * WAVE_REGION)         // 53248 >= 50000
#define DEG_BINS 1024

typedef __attribute__((ext_vector_type(8))) unsigned short ushort8_t;
typedef __attribute__((ext_vector_type(8))) short bf16x8;
typedef __attribute__((ext_vector_type(4))) float f32x4;

// RNE float -> bf16
__device__ __forceinline__ unsigned short f2bf(float x) {
  unsigned u = __float_as_uint(x);
  u += 0x7fffu + ((u >> 16) & 1u);
  return (unsigned short)(u >> 16);
}
__device__ __forceinline__ float bf2f(unsigned short h) {
  return __uint_as_float((unsigned)h << 16);
}

// ============ CSR build (once per call) ====================================
// rank[e] = position of edge e among edges with the same dst (atomic order)
__global__ __launch_bounds__(256) void k_rank(const int* __restrict__ dst,
        int* __restrict__ counts, int* __restrict__ rank, int E) {
  int e = blockIdx.x * 256 + threadIdx.x;
  if (e < E) rank[e] = atomicAdd(&counts[dst[e]], 1);
}

// Single-WG coalesced scan: wave w owns contiguous region of 3328 counts.
__global__ __launch_bounds__(1024) void k_scan_all(const int* __restrict__ counts,
        int* __restrict__ row_ptr, int n) {
  __shared__ int wtot[16];
  int t = threadIdx.x;
  int lane = t & 63, w = t >> 6;
  int rb = w * WAVE_REGION;
  int tot = 0;
  for (int j = 0; j < 52; ++j) tot += counts[rb + j * 64 + lane];
#pragma unroll
  for (int d = 1; d < 64; d <<= 1) tot += __shfl_xor(tot, d);
  if (lane == 0) wtot[w] = tot;
  __syncthreads();
  int wbase = 0;
#pragma unroll
  for (int i = 0; i < 16; ++i) wbase += (i < w) ? wtot[i] : 0;
  int running = wbase;
  for (int j = 0; j < 52; ++j) {
    int idx = rb + j * 64 + lane;
    int v = counts[idx];
    int incl = v;
#pragma unroll
    for (int d = 1; d < 64; d <<= 1) {
      int u = __shfl_up(incl, d);
      if (lane >= d) incl += u;
    }
    if (idx < n) row_ptr[idx + 1] = running + incl;
    running += __shfl(incl, 63);
  }
  if (t == 0) row_ptr[0] = 0;
}

// atomic-free placement: slot = row_ptr[dst] + rank
__global__ __launch_bounds__(256) void k_place(const int* __restrict__ src,
        const int* __restrict__ dst, const int* __restrict__ rank,
        const int* __restrict__ row_ptr, int* __restrict__ col_src, int E) {
  int e = blockIdx.x * 256 + threadIdx.x;
  if (e >= E) return;
  col_src[row_ptr[dst[e]] + rank[e]] = src[e];
}

// ---- degree counting-sort, single WG, LDS-resident bins -------------------
// Degrees are Poisson(16) -> ~30 hot bins; global atomics on those bins
// serialize at L2 latency (round-12 regression: 147us). LDS atomics make the
// same chains ~20x cheaper, and one WG removes all cross-kernel handoffs.
__global__ __launch_bounds__(1024) void k_deg_sort(const int* __restrict__ row_ptr,
        int* __restrict__ node_order, int n) {
  __shared__ int hist[DEG_BINS];
  int t = threadIdx.x;
  hist[t] = 0;
  __syncthreads();
  for (int i = t; i < n; i += 1024) {
    int d = row_ptr[i + 1] - row_ptr[i];
    if (d > DEG_BINS - 1) d = DEG_BINS - 1;
    atomicAdd(&hist[d], 1);
  }
  __syncthreads();
  // exclusive scan of hist in LDS
  int v = hist[t];
  for (int off = 1; off < DEG_BINS; off <<= 1) {
    int u = (t >= off) ? hist[t - off] : 0;
    __syncthreads();
    hist[t] += u;
    __syncthreads();
  }
  int excl = hist[t] - v;
  __syncthreads();
  hist[t] = excl;          // cursor base per bin
  __syncthreads();
  for (int i = t; i < n; i += 1024) {
    int d = row_ptr[i + 1] - row_ptr[i];
    if (d > DEG_BINS - 1) d = DEG_BINS - 1;
    int pos = atomicAdd(&hist[d], 1);
    node_order[pos] = i;
  }
}

// ============ one-time converts ============================================

__global__ __launch_bounds__(256) void k_cvt_x(const float* __restrict__ x,
        unsigned short* __restrict__ xb, int total8) {
  int i = blockIdx.x * 256 + threadIdx.x;
  if (i >= total8) return;
  float4 a = ((const float4*)x)[2 * i];
  float4 b = ((const float4*)x)[2 * i + 1];
  uint4 pk;
  pk.x = (unsigned)f2bf(a.x) | ((unsigned)f2bf(a.y) << 16);
  pk.y = (unsigned)f2bf(a.z) | ((unsigned)f2bf(a.w) << 16);
  pk.z = (unsigned)f2bf(b.x) | ((unsigned)f2bf(b.y) << 16);
  pk.w = (unsigned)f2bf(b.z) | ((unsigned)f2bf(b.w) << 16);
  ((uint4*)xb)[i] = pk;
}

// W[l,s][k][col] f32 -> wt[(2l+s)][col][k] bf16 (transposed, K-contiguous)
__global__ void k_cvt_w(const float* __restrict__ Wl, const float* __restrict__ Wr,
        unsigned short* __restrict__ wt) {
  int ls = blockIdx.x;           // 0..5 = layer*2 + side
  int l = ls >> 1, s = ls & 1;
  const float* W = (s ? Wr : Wl) + l * D * D;
  unsigned short* o = wt + ls * D * D;
  for (int it = 0; it < 64; ++it) {
    int idx = it * 256 + threadIdx.x;
    int k = idx >> 7, c = idx & 127;
    o[c * D + k] = f2bf(W[idx]);
  }
}

// ============ GEMM: bf16 MFMA 16x16x32 =====================================
__global__ __launch_bounds__(256) void k_gemm(const unsigned short* __restrict__ xb,
        const unsigned short* __restrict__ wt,   // this layer: [2][128 col][128 k]
        unsigned short* __restrict__ xlb, unsigned short* __restrict__ xrb, int n) {
  __shared__ unsigned short xs[128 * 128];   // 32 KB
  const int t = threadIdx.x;
  const int row0 = blockIdx.x * 128;
  const unsigned short* __restrict__ W = wt + (size_t)blockIdx.y * (D * D);
  unsigned short* __restrict__ outp = blockIdx.y ? xrb : xlb;

#pragma unroll
  for (int i = 0; i < 8; ++i) {
    int ci = i * 256 + t;          // 16B-chunk index 0..2047
    int lr = ci >> 4, p = ci & 15;
    int grow = row0 + lr;
    if (grow >= n) grow = n - 1;   // clamped rows are never stored
    int gp = p ^ (lr & 7);
    uint4 v = *(const uint4*)(xb + (size_t)grow * D + gp * 8);
    *(uint4*)((char*)xs + ci * 16) = v;
  }
  __syncthreads();

  const int lane = t & 63, wv = t >> 6;
  const int colg = lane & 15, kg = lane >> 4;

  f32x4 acc[2][8];
#pragma unroll
  for (int rr = 0; rr < 2; ++rr)
#pragma unroll
    for (int cc = 0; cc < 8; ++cc) acc[rr][cc] = (f32x4)(0.f);

#pragma unroll
  for (int ks = 0; ks < 4; ++ks) {
    bf16x8 a[2], b[8];
#pragma unroll
    for (int rr = 0; rr < 2; ++rr) {
      int lr = wv * 32 + rr * 16 + colg;
      int byte = (lr * 256 + ks * 64 + kg * 16) ^ ((lr & 7) << 4);
      a[rr] = *(const bf16x8*)((const char*)xs + byte);
    }
#pragma unroll
    for (int cc = 0; cc < 8; ++cc) {
      int col = cc * 16 + colg;
      b[cc] = *(const bf16x8*)(W + (size_t)col * D + ks * 32 + kg * 8);
    }
#pragma unroll
    for (int rr = 0; rr < 2; ++rr)
#pragma unroll
      for (int cc = 0; cc < 8; ++cc)
        acc[rr][cc] = __builtin_amdgcn_mfma_f32_16x16x32_bf16(a[rr], b[cc], acc[rr][cc], 0, 0, 0);
  }

#pragma unroll
  for (int rr = 0; rr < 2; ++rr) {
    int rbase = row0 + wv * 32 + rr * 16 + kg * 4;
#pragma unroll
    for (int cc = 0; cc < 8; ++cc) {
      int col = cc * 16 + colg;
      f32x4 v = acc[rr][cc];
#pragma unroll
      for (int r = 0; r < 4; ++r) {
        int grow = rbase + r;
        if (grow < n) outp[(size_t)grow * D + col] = f2bf(v[r]);
      }
    }
  }
}

// ============ fused score + online-softmax + aggregate =====================
// 16 lanes per node (degree-sorted order), batch-4 gather pipelining.

__device__ __forceinline__ void agg_step(ushort8_t hv, const float* xrv,
        const float* atv, float& m, float& den, float* ac) {
  float v[8];
#pragma unroll
  for (int j = 0; j < 8; ++j) v[j] = bf2f(hv[j]);
  float p = 0.f;
#pragma unroll
  for (int j = 0; j < 8; ++j) {
    float tt = v[j] + xrv[j];
    tt = tt > 0.f ? tt : NEG_SLOPE * tt;
    p += tt * atv[j];
  }
  p += __shfl_xor(p, 1);
  p += __shfl_xor(p, 2);
  p += __shfl_xor(p, 4);
  p += __shfl_xor(p, 8);
  if (p > m) {
    float sc = __expf(m - p);
    den *= sc;
#pragma unroll
    for (int j = 0; j < 8; ++j) ac[j] *= sc;
    m = p;
  }
  float a = __expf(p - m);
  den += a;
#pragma unroll
  for (int j = 0; j < 8; ++j) ac[j] += a * v[j];
}

__global__ __launch_bounds__(256) void k_agg(const unsigned short* __restrict__ xlb,
        const unsigned short* __restrict__ xrb, const int* __restrict__ col_src,
        const int* __restrict__ row_ptr, const int* __restrict__ node_order,
        const float* __restrict__ att, float* __restrict__ out, int n) {
  int g = blockIdx.x * 16 + (threadIdx.x >> 4);
  if (g >= n) return;
  int node = node_order[g];
  int lane = threadIdx.x & 15;
  int ro = lane * 2;
  ushort8_t hr = ((const ushort8_t*)(xrb + (size_t)node * D))[lane];
  float xrv[8];
#pragma unroll
  for (int j = 0; j < 8; ++j) xrv[j] = bf2f(hr[j]);
  float4 at0 = ((const float4*)att)[ro];
  float4 at1 = ((const float4*)att)[ro + 1];
  float atv[8] = {at0.x, at0.y, at0.z, at0.w, at1.x, at1.y, at1.z, at1.w};

  int k0 = row_ptr[node], k1 = row_ptr[node + 1];
  float m = -1e30f, den = 0.f;
  float ac[8];
#pragma unroll
  for (int j = 0; j < 8; ++j) ac[j] = 0.f;

  const ushort8_t* xl8 = (const ushort8_t*)xlb;
  int k = k0;
  for (; k + 4 <= k1; k += 4) {
    int s0 = col_src[k], s1 = col_src[k + 1], s2 = col_src[k + 2], s3 = col_src[k + 3];
    ushort8_t h0 = xl8[(size_t)s0 * 16 + lane];
    ushort8_t h1 = xl8[(size_t)s1 * 16 + lane];
    ushort8_t h2 = xl8[(size_t)s2 * 16 + lane];
    ushort8_t h3 = xl8[(size_t)s3 * 16 + lane];
    agg_step(h0, xrv, atv, m, den, ac);
    agg_step(h1, xrv, atv, m, den, ac);
    agg_step(h2, xrv, atv, m, den, ac);
    agg_step(h3, xrv, atv, m, den, ac);
  }
  for (; k < k1; ++k) {
    int s = col_src[k];
    ushort8_t h = xl8[(size_t)s * 16 + lane];
    agg_step(h, xrv, atv, m, den, ac);
  }

  float inv = 1.f / (den + 1e-16f);
  float4* o4 = (float4*)out;
  o4[(size_t)node * 32 + ro]     = make_float4(ac[0] * inv, ac[1] * inv, ac[2] * inv, ac[3] * inv);
  o4[(size_t)node * 32 + ro + 1] = make_float4(ac[4] * inv, ac[5] * inv, ac[6] * inv, ac[7] * inv);
}

// ============ BatchNorm + GELU =============================================

__global__ __launch_bounds__(256) void k_bn_stats(const float* __restrict__ agg,
        float* __restrict__ sums, int n) {
  int c = threadIdx.x & 127;
  int half = threadIdx.x >> 7;
  float s = 0.f, s2 = 0.f;
  for (int r = blockIdx.x * 2 + half; r < n; r += gridDim.x * 2) {
    float v = agg[(size_t)r * D + c];
    s += v;
    s2 += v * v;
  }
  atomicAdd(&sums[c], s);
  atomicAdd(&sums[D + c], s2);
}

__global__ void k_bn_fin(const float* __restrict__ sums, const float* __restrict__ gamma,
        const float* __restrict__ beta, float* __restrict__ ss, float inv_n) {
  int c = threadIdx.x;
  float mu = sums[c] * inv_n;
  float var = sums[D + c] * inv_n - mu * mu;
  float rs = rsqrtf(var + BN_EPS);
  float sc = gamma[c] * rs;
  ss[c] = sc;
  ss[D + c] = beta[c] - mu * sc;
}

// writes f32 result AND bf16 mirror (next layer's GEMM input)
__global__ __launch_bounds__(256) void k_bn_apply(const float* __restrict__ agg,
        const float* __restrict__ ss, float* __restrict__ xo,
        unsigned short* __restrict__ xbo, int total4) {
  int i = blockIdx.x * 256 + threadIdx.x;
  if (i >= total4) return;
  float4 v = ((const float4*)agg)[i];
  int c4 = i & (D / 4 - 1);
  float4 sc = ((const float4*)ss)[c4];
  float4 sh = ((const float4*)ss)[D / 4 + c4];
  float y0 = sc.x * v.x + sh.x;
  float y1 = sc.y * v.y + sh.y;
  float y2 = sc.z * v.z + sh.z;
  float y3 = sc.w * v.w + sh.w;
  float4 g;
  g.x = 0.5f * y0 * (1.f + erff(y0 * 0.70710678118654752f));
  g.y = 0.5f * y1 * (1.f + erff(y1 * 0.70710678118654752f));
  g.z = 0.5f * y2 * (1.f + erff(y2 * 0.70710678118654752f));
  g.w = 0.5f * y3 * (1.f + erff(y3 * 0.70710678118654752f));
  ((float4*)xo)[i] = g;
  uint2 pk;
  pk.x = (unsigned)f2bf(g.x) | ((unsigned)f2bf(g.y) << 16);
  pk.y = (unsigned)f2bf(g.z) | ((unsigned)f2bf(g.w) << 16);
  ((uint2*)xbo)[i] = pk;
}

// ===========================================================================

extern "C" void kernel_launch(void* const* d_in, const int* in_sizes, int n_in,
                              void* d_out, int out_size, void* d_ws, size_t ws_size,
                              hipStream_t stream) {
  const float* x0    = (const float*)d_in[0];
  const int*   ei    = (const int*)d_in[1];
  const float* Wl    = (const float*)d_in[2];
  const float* Wr    = (const float*)d_in[3];
  const float* att   = (const float*)d_in[4];
  // d_in[5] = bias: cancelled exactly by BatchNorm mean-subtraction; unused.
  const float* gamma = (const float*)d_in[6];
  const float* beta  = (const float*)d_in[7];
  float* out = (float*)d_out;

  float* ws = (float*)d_ws;
  unsigned short* xb  = (unsigned short*)ws;              // [N][128] bf16
  unsigned short* xlb = (unsigned short*)(ws + 3200000);  // [N][128] bf16
  unsigned short* xrb = (unsigned short*)(ws + 6400000);  // [N][128] bf16
  int*   col_src    = (int*)(ws + 9600000);       //   800,000
  int*   rank       = (int*)(ws + 10400000);      //   800,000
  int*   row_ptr    = (int*)(ws + 11200000);      //    50,001
  int*   counts     = (int*)(ws + 11250004);      // COUNTS_PAD (53,248)
  int*   node_order = (int*)(ws + 11303252);      //    50,000
  float* sums       = ws + 11353252;              //       256
  float* ss         = ws + 11353508;              //       256
  unsigned short* wt = (unsigned short*)(ws + 11353764);  // [3][2][128][128] bf16

  const int* src = ei;
  const int* dst = ei + NEDGES;

  // ---- one-time: CSR build + degree sort + converts ----
  hipMemsetAsync(counts, 0, COUNTS_PAD * sizeof(int), stream);
  k_rank<<<(NEDGES + 255) / 256, 256, 0, stream>>>(dst, counts, rank, NEDGES);
  k_scan_all<<<1, SCAN_THREADS, 0, stream>>>(counts, row_ptr, NNODES);
  k_place<<<(NEDGES + 255) / 256, 256, 0, stream>>>(src, dst, rank, row_ptr, col_src, NEDGES);
  k_deg_sort<<<1, DEG_BINS, 0, stream>>>(row_ptr, node_order, NNODES);
  k_cvt_w<<<6, 256, 0, stream>>>(Wl, Wr, wt);
  k_cvt_x<<<(NNODES * (D / 8) + 255) / 256, 256, 0, stream>>>(x0, xb, NNODES * (D / 8));

  dim3 ggrid((NNODES + 127) / 128, 2);

  for (int l = 0; l < 3; ++l) {
    k_gemm<<<ggrid, 256, 0, stream>>>(xb, wt + (size_t)l * 2 * D * D, xlb, xrb, NNODES);
    hipMemsetAsync(sums, 0, 2 * D * sizeof(float), stream);

    // d_out is dead as an input after k_gemm -> safe to overwrite with agg.
    k_agg<<<(NNODES + 15) / 16, 256, 0, stream>>>(xlb, xrb, col_src, row_ptr,
                                                  node_order, att + l * D, out, NNODES);

    k_bn_stats<<<512, 256, 0, stream>>>(out, sums, NNODES);
    k_bn_fin<<<1, D, 0, stream>>>(sums, gamma + l * D, beta + l * D, ss, 1.0f / NNODES);
    k_bn_apply<<<(NNODES * (D / 4) + 255) / 256, 256, 0, stream>>>(out, ss, out, xb,
                                                                   NNODES * (D / 4));
  }
}

// Round 14
// 499.427 us; speedup vs baseline: 1.5609x; 1.0201x over previous
//
#include <hip/hip_runtime.h>
#include <math.h>

#define NNODES 50000
#define NEDGES 800000
#define D 128
#define NEG_SLOPE 0.2f
#define BN_EPS 1e-5f
#define SCAN_THREADS 1024
#define WAVE_REGION 3328                      // 52 elems x 64 lanes
#define COUNTS_PAD (16 * WAVE_REGION)         // 53248 >= 50000
#define DEG_BINS 1024
#define BN_NB 625                             // 625 blocks x 80 rows = 50000
#define BN_ROWS 80

typedef __attribute__((ext_vector_type(8))) unsigned short ushort8_t;
typedef __attribute__((ext_vector_type(8))) short bf16x8;
typedef __attribute__((ext_vector_type(4))) float f32x4;

// RNE float -> bf16
__device__ __forceinline__ unsigned short f2bf(float x) {
  unsigned u = __float_as_uint(x);
  u += 0x7fffu + ((u >> 16) & 1u);
  return (unsigned short)(u >> 16);
}
__device__ __forceinline__ float bf2f(unsigned short h) {
  return __uint_as_float((unsigned)h << 16);
}

// ============ CSR build (once per call) ====================================
// rank[e] = position of edge e among edges with the same dst (atomic order)
__global__ __launch_bounds__(256) void k_rank(const int* __restrict__ dst,
        int* __restrict__ counts, int* __restrict__ rank, int E) {
  int e = blockIdx.x * 256 + threadIdx.x;
  if (e < E) rank[e] = atomicAdd(&counts[dst[e]], 1);
}

// Single-WG coalesced scan: wave w owns contiguous region of 3328 counts.
__global__ __launch_bounds__(1024) void k_scan_all(const int* __restrict__ counts,
        int* __restrict__ row_ptr, int n) {
  __shared__ int wtot[16];
  int t = threadIdx.x;
  int lane = t & 63, w = t >> 6;
  int rb = w * WAVE_REGION;
  int tot = 0;
  for (int j = 0; j < 52; ++j) tot += counts[rb + j * 64 + lane];
#pragma unroll
  for (int d = 1; d < 64; d <<= 1) tot += __shfl_xor(tot, d);
  if (lane == 0) wtot[w] = tot;
  __syncthreads();
  int wbase = 0;
#pragma unroll
  for (int i = 0; i < 16; ++i) wbase += (i < w) ? wtot[i] : 0;
  int running = wbase;
  for (int j = 0; j < 52; ++j) {
    int idx = rb + j * 64 + lane;
    int v = counts[idx];
    int incl = v;
#pragma unroll
    for (int d = 1; d < 64; d <<= 1) {
      int u = __shfl_up(incl, d);
      if (lane >= d) incl += u;
    }
    if (idx < n) row_ptr[idx + 1] = running + incl;
    running += __shfl(incl, 63);
  }
  if (t == 0) row_ptr[0] = 0;
}

// atomic-free placement: slot = row_ptr[dst] + rank
__global__ __launch_bounds__(256) void k_place(const int* __restrict__ src,
        const int* __restrict__ dst, const int* __restrict__ rank,
        const int* __restrict__ row_ptr, int* __restrict__ col_src, int E) {
  int e = blockIdx.x * 256 + threadIdx.x;
  if (e >= E) return;
  col_src[row_ptr[dst[e]] + rank[e]] = src[e];
}

// ---- degree counting-sort, single WG, LDS-resident bins -------------------
__global__ __launch_bounds__(1024) void k_deg_sort(const int* __restrict__ row_ptr,
        int* __restrict__ node_order, int n) {
  __shared__ int hist[DEG_BINS];
  int t = threadIdx.x;
  hist[t] = 0;
  __syncthreads();
  for (int i = t; i < n; i += 1024) {
    int d = row_ptr[i + 1] - row_ptr[i];
    if (d > DEG_BINS - 1) d = DEG_BINS - 1;
    atomicAdd(&hist[d], 1);
  }
  __syncthreads();
  int v = hist[t];
  for (int off = 1; off < DEG_BINS; off <<= 1) {
    int u = (t >= off) ? hist[t - off] : 0;
    __syncthreads();
    hist[t] += u;
    __syncthreads();
  }
  int excl = hist[t] - v;
  __syncthreads();
  hist[t] = excl;          // cursor base per bin
  __syncthreads();
  for (int i = t; i < n; i += 1024) {
    int d = row_ptr[i + 1] - row_ptr[i];
    if (d > DEG_BINS - 1) d = DEG_BINS - 1;
    int pos = atomicAdd(&hist[d], 1);
    node_order[pos] = i;
  }
}

// ============ one-time converts ============================================

__global__ __launch_bounds__(256) void k_cvt_x(const float* __restrict__ x,
        unsigned short* __restrict__ xb, int total8) {
  int i = blockIdx.x * 256 + threadIdx.x;
  if (i >= total8) return;
  float4 a = ((const float4*)x)[2 * i];
  float4 b = ((const float4*)x)[2 * i + 1];
  uint4 pk;
  pk.x = (unsigned)f2bf(a.x) | ((unsigned)f2bf(a.y) << 16);
  pk.y = (unsigned)f2bf(a.z) | ((unsigned)f2bf(a.w) << 16);
  pk.z = (unsigned)f2bf(b.x) | ((unsigned)f2bf(b.y) << 16);
  pk.w = (unsigned)f2bf(b.z) | ((unsigned)f2bf(b.w) << 16);
  ((uint4*)xb)[i] = pk;
}

// W[l,s][k][col] f32 -> wt[(2l+s)][col][k] bf16 (transposed, K-contiguous)
__global__ void k_cvt_w(const float* __restrict__ Wl, const float* __restrict__ Wr,
        unsigned short* __restrict__ wt) {
  int ls = blockIdx.x;           // 0..5 = layer*2 + side
  int l = ls >> 1, s = ls & 1;
  const float* W = (s ? Wr : Wl) + l * D * D;
  unsigned short* o = wt + ls * D * D;
  for (int it = 0; it < 64; ++it) {
    int idx = it * 256 + threadIdx.x;
    int k = idx >> 7, c = idx & 127;
    o[c * D + k] = f2bf(W[idx]);
  }
}

// ============ GEMM: bf16 MFMA 16x16x32 =====================================
__global__ __launch_bounds__(256) void k_gemm(const unsigned short* __restrict__ xb,
        const unsigned short* __restrict__ wt,   // this layer: [2][128 col][128 k]
        unsigned short* __restrict__ xlb, unsigned short* __restrict__ xrb, int n) {
  __shared__ unsigned short xs[128 * 128];   // 32 KB
  const int t = threadIdx.x;
  const int row0 = blockIdx.x * 128;
  const unsigned short* __restrict__ W = wt + (size_t)blockIdx.y * (D * D);
  unsigned short* __restrict__ outp = blockIdx.y ? xrb : xlb;

#pragma unroll
  for (int i = 0; i < 8; ++i) {
    int ci = i * 256 + t;          // 16B-chunk index 0..2047
    int lr = ci >> 4, p = ci & 15;
    int grow = row0 + lr;
    if (grow >= n) grow = n - 1;   // clamped rows are never stored
    int gp = p ^ (lr & 7);
    uint4 v = *(const uint4*)(xb + (size_t)grow * D + gp * 8);
    *(uint4*)((char*)xs + ci * 16) = v;
  }
  __syncthreads();

  const int lane = t & 63, wv = t >> 6;
  const int colg = lane & 15, kg = lane >> 4;

  f32x4 acc[2][8];
#pragma unroll
  for (int rr = 0; rr < 2; ++rr)
#pragma unroll
    for (int cc = 0; cc < 8; ++cc) acc[rr][cc] = (f32x4)(0.f);

#pragma unroll
  for (int ks = 0; ks < 4; ++ks) {
    bf16x8 a[2], b[8];
#pragma unroll
    for (int rr = 0; rr < 2; ++rr) {
      int lr = wv * 32 + rr * 16 + colg;
      int byte = (lr * 256 + ks * 64 + kg * 16) ^ ((lr & 7) << 4);
      a[rr] = *(const bf16x8*)((const char*)xs + byte);
    }
#pragma unroll
    for (int cc = 0; cc < 8; ++cc) {
      int col = cc * 16 + colg;
      b[cc] = *(const bf16x8*)(W + (size_t)col * D + ks * 32 + kg * 8);
    }
#pragma unroll
    for (int rr = 0; rr < 2; ++rr)
#pragma unroll
      for (int cc = 0; cc < 8; ++cc)
        acc[rr][cc] = __builtin_amdgcn_mfma_f32_16x16x32_bf16(a[rr], b[cc], acc[rr][cc], 0, 0, 0);
  }

#pragma unroll
  for (int rr = 0; rr < 2; ++rr) {
    int rbase = row0 + wv * 32 + rr * 16 + kg * 4;
#pragma unroll
    for (int cc = 0; cc < 8; ++cc) {
      int col = cc * 16 + colg;
      f32x4 v = acc[rr][cc];
#pragma unroll
      for (int r = 0; r < 4; ++r) {
        int grow = rbase + r;
        if (grow < n) outp[(size_t)grow * D + col] = f2bf(v[r]);
      }
    }
  }
}

// ============ fused score + online-softmax + aggregate =====================
// 16 lanes per node (degree-sorted order), batch-4 gather pipelining.

__device__ __forceinline__ void agg_step(ushort8_t hv, const float* xrv,
        const float* atv, float& m, float& den, float* ac) {
  float v[8];
#pragma unroll
  for (int j = 0; j < 8; ++j) v[j] = bf2f(hv[j]);
  float p = 0.f;
#pragma unroll
  for (int j = 0; j < 8; ++j) {
    float tt = v[j] + xrv[j];
    tt = tt > 0.f ? tt : NEG_SLOPE * tt;
    p += tt * atv[j];
  }
  p += __shfl_xor(p, 1);
  p += __shfl_xor(p, 2);
  p += __shfl_xor(p, 4);
  p += __shfl_xor(p, 8);
  if (p > m) {
    float sc = __expf(m - p);
    den *= sc;
#pragma unroll
    for (int j = 0; j < 8; ++j) ac[j] *= sc;
    m = p;
  }
  float a = __expf(p - m);
  den += a;
#pragma unroll
  for (int j = 0; j < 8; ++j) ac[j] += a * v[j];
}

__global__ __launch_bounds__(256) void k_agg(const unsigned short* __restrict__ xlb,
        const unsigned short* __restrict__ xrb, const int* __restrict__ col_src,
        const int* __restrict__ row_ptr, const int* __restrict__ node_order,
        const float* __restrict__ att, float* __restrict__ out, int n) {
  int g = blockIdx.x * 16 + (threadIdx.x >> 4);
  if (g >= n) return;
  int node = node_order[g];
  int lane = threadIdx.x & 15;
  int ro = lane * 2;
  ushort8_t hr = ((const ushort8_t*)(xrb + (size_t)node * D))[lane];
  float xrv[8];
#pragma unroll
  for (int j = 0; j < 8; ++j) xrv[j] = bf2f(hr[j]);
  float4 at0 = ((const float4*)att)[ro];
  float4 at1 = ((const float4*)att)[ro + 1];
  float atv[8] = {at0.x, at0.y, at0.z, at0.w, at1.x, at1.y, at1.z, at1.w};

  int k0 = row_ptr[node], k1 = row_ptr[node + 1];
  float m = -1e30f, den = 0.f;
  float ac[8];
#pragma unroll
  for (int j = 0; j < 8; ++j) ac[j] = 0.f;

  const ushort8_t* xl8 = (const ushort8_t*)xlb;
  int k = k0;
  for (; k + 4 <= k1; k += 4) {
    int s0 = col_src[k], s1 = col_src[k + 1], s2 = col_src[k + 2], s3 = col_src[k + 3];
    ushort8_t h0 = xl8[(size_t)s0 * 16 + lane];
    ushort8_t h1 = xl8[(size_t)s1 * 16 + lane];
    ushort8_t h2 = xl8[(size_t)s2 * 16 + lane];
    ushort8_t h3 = xl8[(size_t)s3 * 16 + lane];
    agg_step(h0, xrv, atv, m, den, ac);
    agg_step(h1, xrv, atv, m, den, ac);
    agg_step(h2, xrv, atv, m, den, ac);
    agg_step(h3, xrv, atv, m, den, ac);
  }
  for (; k < k1; ++k) {
    int s = col_src[k];
    ushort8_t h = xl8[(size_t)s * 16 + lane];
    agg_step(h, xrv, atv, m, den, ac);
  }

  float inv = 1.f / (den + 1e-16f);
  float4* o4 = (float4*)out;
  o4[(size_t)node * 32 + ro]     = make_float4(ac[0] * inv, ac[1] * inv, ac[2] * inv, ac[3] * inv);
  o4[(size_t)node * 32 + ro + 1] = make_float4(ac[4] * inv, ac[5] * inv, ac[6] * inv, ac[7] * inv);
}

// ============ BatchNorm + GELU =============================================
// Stage 1: per-block (80 rows) partial sum/sumsq, no atomics.
// Thread layout: 32 col-groups (float4) x 8 row-groups.
__global__ __launch_bounds__(256) void k_bn_part(const float* __restrict__ agg,
        float* __restrict__ partial) {
  __shared__ float4 lsum[256], lsq[256];
  int t = threadIdx.x;
  int cg = t & 31, rg = t >> 5;
  int rbase = blockIdx.x * BN_ROWS;
  float4 s = make_float4(0.f, 0.f, 0.f, 0.f);
  float4 q = make_float4(0.f, 0.f, 0.f, 0.f);
#pragma unroll
  for (int p = 0; p < BN_ROWS / 8; ++p) {
    int r = rbase + p * 8 + rg;
    float4 v = ((const float4*)agg)[(size_t)r * 32 + cg];
    s.x += v.x; s.y += v.y; s.z += v.z; s.w += v.w;
    q.x += v.x * v.x; q.y += v.y * v.y; q.z += v.z * v.z; q.w += v.w * v.w;
  }
  lsum[t] = s; lsq[t] = q;
  __syncthreads();
  if (t < 32) {
    float4 a = lsum[t];
#pragma unroll
    for (int j = 1; j < 8; ++j) {
      float4 b = lsum[j * 32 + t];
      a.x += b.x; a.y += b.y; a.z += b.z; a.w += b.w;
    }
    ((float4*)(partial + (size_t)blockIdx.x * 256))[t] = a;
  } else if (t < 64) {
    int c = t - 32;
    float4 a = lsq[c];
#pragma unroll
    for (int j = 1; j < 8; ++j) {
      float4 b = lsq[j * 32 + c];
      a.x += b.x; a.y += b.y; a.z += b.z; a.w += b.w;
    }
    ((float4*)(partial + (size_t)blockIdx.x * 256 + 128))[c] = a;
  }
}

// Stage 2: reduce 625 partial records, emit scale/shift directly.
__global__ void k_bn_fin2(const float* __restrict__ partial,
        const float* __restrict__ gamma, const float* __restrict__ beta,
        float* __restrict__ ss, float inv_n) {
  __shared__ float lds[256];
  int t = threadIdx.x;
  float acc = 0.f;
  for (int b = 0; b < BN_NB; ++b) acc += partial[(size_t)b * 256 + t];
  lds[t] = acc;
  __syncthreads();
  if (t < 128) {
    float mu = lds[t] * inv_n;
    float var = lds[128 + t] * inv_n - mu * mu;
    float rs = rsqrtf(var + BN_EPS);
    float sc = gamma[t] * rs;
    ss[t] = sc;
    ss[128 + t] = beta[t] - mu * sc;
  }
}

// writes f32 result AND bf16 mirror (next layer's GEMM input)
__global__ __launch_bounds__(256) void k_bn_apply(const float* __restrict__ agg,
        const float* __restrict__ ss, float* __restrict__ xo,
        unsigned short* __restrict__ xbo, int total4) {
  int i = blockIdx.x * 256 + threadIdx.x;
  if (i >= total4) return;
  float4 v = ((const float4*)agg)[i];
  int c4 = i & (D / 4 - 1);
  float4 sc = ((const float4*)ss)[c4];
  float4 sh = ((const float4*)ss)[D / 4 + c4];
  float y0 = sc.x * v.x + sh.x;
  float y1 = sc.y * v.y + sh.y;
  float y2 = sc.z * v.z + sh.z;
  float y3 = sc.w * v.w + sh.w;
  float4 g;
  g.x = 0.5f * y0 * (1.f + erff(y0 * 0.70710678118654752f));
  g.y = 0.5f * y1 * (1.f + erff(y1 * 0.70710678118654752f));
  g.z = 0.5f * y2 * (1.f + erff(y2 * 0.70710678118654752f));
  g.w = 0.5f * y3 * (1.f + erff(y3 * 0.70710678118654752f));
  ((float4*)xo)[i] = g;
  uint2 pk;
  pk.x = (unsigned)f2bf(g.x) | ((unsigned)f2bf(g.y) << 16);
  pk.y = (unsigned)f2bf(g.z) | ((unsigned)f2bf(g.w) << 16);
  ((uint2*)xbo)[i] = pk;
}

// ===========================================================================

extern "C" void kernel_launch(void* const* d_in, const int* in_sizes, int n_in,
                              void* d_out, int out_size, void* d_ws, size_t ws_size,
                              hipStream_t stream) {
  const float* x0    = (const float*)d_in[0];
  const int*   ei    = (const int*)d_in[1];
  const float* Wl    = (const float*)d_in[2];
  const float* Wr    = (const float*)d_in[3];
  const float* att   = (const float*)d_in[4];
  // d_in[5] = bias: cancelled exactly by BatchNorm mean-subtraction; unused.
  const float* gamma = (const float*)d_in[6];
  const float* beta  = (const float*)d_in[7];
  float* out = (float*)d_out;

  float* ws = (float*)d_ws;
  unsigned short* xb  = (unsigned short*)ws;              // [N][128] bf16
  unsigned short* xlb = (unsigned short*)(ws + 3200000);  // [N][128] bf16
  unsigned short* xrb = (unsigned short*)(ws + 6400000);  // [N][128] bf16
  int*   col_src    = (int*)(ws + 9600000);       //   800,000
  int*   rank       = (int*)(ws + 10400000);      //   800,000
  int*   row_ptr    = (int*)(ws + 11200000);      //    50,001
  int*   counts     = (int*)(ws + 11250004);      // COUNTS_PAD (53,248)
  int*   node_order = (int*)(ws + 11303252);      //    50,000
  float* partial    = ws + 11353252;              //   160,000 (625 x 256)
  float* ss         = ws + 11513252;              //       256
  unsigned short* wt = (unsigned short*)(ws + 11513508);  // [3][2][128][128] bf16

  const int* src = ei;
  const int* dst = ei + NEDGES;

  // ---- one-time: CSR build + degree sort + converts ----
  hipMemsetAsync(counts, 0, COUNTS_PAD * sizeof(int), stream);
  k_rank<<<(NEDGES + 255) / 256, 256, 0, stream>>>(dst, counts, rank, NEDGES);
  k_scan_all<<<1, SCAN_THREADS, 0, stream>>>(counts, row_ptr, NNODES);
  k_place<<<(NEDGES + 255) / 256, 256, 0, stream>>>(src, dst, rank, row_ptr, col_src, NEDGES);
  k_deg_sort<<<1, DEG_BINS, 0, stream>>>(row_ptr, node_order, NNODES);
  k_cvt_w<<<6, 256, 0, stream>>>(Wl, Wr, wt);
  k_cvt_x<<<(NNODES * (D / 8) + 255) / 256, 256, 0, stream>>>(x0, xb, NNODES * (D / 8));

  dim3 ggrid((NNODES + 127) / 128, 2);

  for (int l = 0; l < 3; ++l) {
    k_gemm<<<ggrid, 256, 0, stream>>>(xb, wt + (size_t)l * 2 * D * D, xlb, xrb, NNODES);

    // d_out is dead as an input after k_gemm -> safe to overwrite with agg.
    k_agg<<<(NNODES + 15) / 16, 256, 0, stream>>>(xlb, xrb, col_src, row_ptr,
                                                  node_order, att + l * D, out, NNODES);

    k_bn_part<<<BN_NB, 256, 0, stream>>>(out, partial);
    k_bn_fin2<<<1, 256, 0, stream>>>(partial, gamma + l * D, beta + l * D, ss, 1.0f / NNODES);
    k_bn_apply<<<(NNODES * (D / 4) + 255) / 256, 256, 0, stream>>>(out, ss, out, xb,
                                                                   NNODES * (D / 4));
  }
}

// Round 15
// 486.696 us; speedup vs baseline: 1.6017x; 1.0262x over previous
//
#include <hip/hip_runtime.h>
#include <math.h>

#define NNODES 50000
#define NEDGES 800000
#define D 128
#define NEG_SLOPE 0.2f
#define BN_EPS 1e-5f
#define SCAN_THREADS 1024
#define WAVE_REGION 3328                      // 52 elems x 64 lanes
#define COUNTS_PAD (16 * WAVE_REGION)         // 53248 >= 50000
#define DEG_BINS 1024
#define BN_NB 625                             // 625 blocks x 80 rows = 50000
#define BN_ROWS 80

typedef __attribute__((ext_vector_type(8))) unsigned short ushort8_t;
typedef __attribute__((ext_vector_type(8))) short bf16x8;
typedef __attribute__((ext_vector_type(4))) float f32x4;

// RNE float -> bf16
__device__ __forceinline__ unsigned short f2bf(float x) {
  unsigned u = __float_as_uint(x);
  u += 0x7fffu + ((u >> 16) & 1u);
  return (unsigned short)(u >> 16);
}
__device__ __forceinline__ float bf2f(unsigned short h) {
  return __uint_as_float((unsigned)h << 16);
}

// ============ CSR build (once per call) ====================================
// rank[e] = position of edge e among edges with the same dst (atomic order)
__global__ __launch_bounds__(256) void k_rank(const int* __restrict__ dst,
        int* __restrict__ counts, int* __restrict__ rank, int E) {
  int e = blockIdx.x * 256 + threadIdx.x;
  if (e < E) rank[e] = atomicAdd(&counts[dst[e]], 1);
}

// Single-WG coalesced scan: wave w owns contiguous region of 3328 counts.
__global__ __launch_bounds__(1024) void k_scan_all(const int* __restrict__ counts,
        int* __restrict__ row_ptr, int n) {
  __shared__ int wtot[16];
  int t = threadIdx.x;
  int lane = t & 63, w = t >> 6;
  int rb = w * WAVE_REGION;
  int tot = 0;
  for (int j = 0; j < 52; ++j) tot += counts[rb + j * 64 + lane];
#pragma unroll
  for (int d = 1; d < 64; d <<= 1) tot += __shfl_xor(tot, d);
  if (lane == 0) wtot[w] = tot;
  __syncthreads();
  int wbase = 0;
#pragma unroll
  for (int i = 0; i < 16; ++i) wbase += (i < w) ? wtot[i] : 0;
  int running = wbase;
  for (int j = 0; j < 52; ++j) {
    int idx = rb + j * 64 + lane;
    int v = counts[idx];
    int incl = v;
#pragma unroll
    for (int d = 1; d < 64; d <<= 1) {
      int u = __shfl_up(incl, d);
      if (lane >= d) incl += u;
    }
    if (idx < n) row_ptr[idx + 1] = running + incl;
    running += __shfl(incl, 63);
  }
  if (t == 0) row_ptr[0] = 0;
}

// atomic-free placement: slot = row_ptr[dst] + rank
__global__ __launch_bounds__(256) void k_place(const int* __restrict__ src,
        const int* __restrict__ dst, const int* __restrict__ rank,
        const int* __restrict__ row_ptr, int* __restrict__ col_src, int E) {
  int e = blockIdx.x * 256 + threadIdx.x;
  if (e >= E) return;
  col_src[row_ptr[dst[e]] + rank[e]] = src[e];
}

// ---- degree counting-sort, single WG, LDS bins. LPT order: DESCENDING
// degree, so the expensive nodes dispatch first and cheap nodes fill the
// grid tail (round-14: ascending order left high-degree blocks draining
// alone at 37% occupancy).
__global__ __launch_bounds__(1024) void k_deg_sort(const int* __restrict__ row_ptr,
        int* __restrict__ node_order, int n) {
  __shared__ int hist[DEG_BINS];
  int t = threadIdx.x;
  hist[t] = 0;
  __syncthreads();
  for (int i = t; i < n; i += 1024) {
    int d = row_ptr[i + 1] - row_ptr[i];
    if (d > DEG_BINS - 1) d = DEG_BINS - 1;
    int bin = (DEG_BINS - 1) - d;          // descending
    atomicAdd(&hist[bin], 1);
  }
  __syncthreads();
  int v = hist[t];
  for (int off = 1; off < DEG_BINS; off <<= 1) {
    int u = (t >= off) ? hist[t - off] : 0;
    __syncthreads();
    hist[t] += u;
    __syncthreads();
  }
  int excl = hist[t] - v;
  __syncthreads();
  hist[t] = excl;          // cursor base per bin
  __syncthreads();
  for (int i = t; i < n; i += 1024) {
    int d = row_ptr[i + 1] - row_ptr[i];
    if (d > DEG_BINS - 1) d = DEG_BINS - 1;
    int bin = (DEG_BINS - 1) - d;
    int pos = atomicAdd(&hist[bin], 1);
    node_order[pos] = i;
  }
}

// ============ one-time converts ============================================

__global__ __launch_bounds__(256) void k_cvt_x(const float* __restrict__ x,
        unsigned short* __restrict__ xb, int total8) {
  int i = blockIdx.x * 256 + threadIdx.x;
  if (i >= total8) return;
  float4 a = ((const float4*)x)[2 * i];
  float4 b = ((const float4*)x)[2 * i + 1];
  uint4 pk;
  pk.x = (unsigned)f2bf(a.x) | ((unsigned)f2bf(a.y) << 16);
  pk.y = (unsigned)f2bf(a.z) | ((unsigned)f2bf(a.w) << 16);
  pk.z = (unsigned)f2bf(b.x) | ((unsigned)f2bf(b.y) << 16);
  pk.w = (unsigned)f2bf(b.z) | ((unsigned)f2bf(b.w) << 16);
  ((uint4*)xb)[i] = pk;
}

// W[l,s][k][col] f32 -> wt[(2l+s)][col][k] bf16 (transposed, K-contiguous)
__global__ void k_cvt_w(const float* __restrict__ Wl, const float* __restrict__ Wr,
        unsigned short* __restrict__ wt) {
  int ls = blockIdx.x;           // 0..5 = layer*2 + side
  int l = ls >> 1, s = ls & 1;
  const float* W = (s ? Wr : Wl) + l * D * D;
  unsigned short* o = wt + ls * D * D;
  for (int it = 0; it < 64; ++it) {
    int idx = it * 256 + threadIdx.x;
    int k = idx >> 7, c = idx & 127;
    o[c * D + k] = f2bf(W[idx]);
  }
}

// ============ GEMM: bf16 MFMA 16x16x32 =====================================
__global__ __launch_bounds__(256) void k_gemm(const unsigned short* __restrict__ xb,
        const unsigned short* __restrict__ wt,   // this layer: [2][128 col][128 k]
        unsigned short* __restrict__ xlb, unsigned short* __restrict__ xrb, int n) {
  __shared__ unsigned short xs[128 * 128];   // 32 KB
  const int t = threadIdx.x;
  const int row0 = blockIdx.x * 128;
  const unsigned short* __restrict__ W = wt + (size_t)blockIdx.y * (D * D);
  unsigned short* __restrict__ outp = blockIdx.y ? xrb : xlb;

#pragma unroll
  for (int i = 0; i < 8; ++i) {
    int ci = i * 256 + t;          // 16B-chunk index 0..2047
    int lr = ci >> 4, p = ci & 15;
    int grow = row0 + lr;
    if (grow >= n) grow = n - 1;   // clamped rows are never stored
    int gp = p ^ (lr & 7);
    uint4 v = *(const uint4*)(xb + (size_t)grow * D + gp * 8);
    *(uint4*)((char*)xs + ci * 16) = v;
  }
  __syncthreads();

  const int lane = t & 63, wv = t >> 6;
  const int colg = lane & 15, kg = lane >> 4;

  f32x4 acc[2][8];
#pragma unroll
  for (int rr = 0; rr < 2; ++rr)
#pragma unroll
    for (int cc = 0; cc < 8; ++cc) acc[rr][cc] = (f32x4)(0.f);

#pragma unroll
  for (int ks = 0; ks < 4; ++ks) {
    bf16x8 a[2], b[8];
#pragma unroll
    for (int rr = 0; rr < 2; ++rr) {
      int lr = wv * 32 + rr * 16 + colg;
      int byte = (lr * 256 + ks * 64 + kg * 16) ^ ((lr & 7) << 4);
      a[rr] = *(const bf16x8*)((const char*)xs + byte);
    }
#pragma unroll
    for (int cc = 0; cc < 8; ++cc) {
      int col = cc * 16 + colg;
      b[cc] = *(const bf16x8*)(W + (size_t)col * D + ks * 32 + kg * 8);
    }
#pragma unroll
    for (int rr = 0; rr < 2; ++rr)
#pragma unroll
      for (int cc = 0; cc < 8; ++cc)
        acc[rr][cc] = __builtin_amdgcn_mfma_f32_16x16x32_bf16(a[rr], b[cc], acc[rr][cc], 0, 0, 0);
  }

#pragma unroll
  for (int rr = 0; rr < 2; ++rr) {
    int rbase = row0 + wv * 32 + rr * 16 + kg * 4;
#pragma unroll
    for (int cc = 0; cc < 8; ++cc) {
      int col = cc * 16 + colg;
      f32x4 v = acc[rr][cc];
#pragma unroll
      for (int r = 0; r < 4; ++r) {
        int grow = rbase + r;
        if (grow < n) outp[(size_t)grow * D + col] = f2bf(v[r]);
      }
    }
  }
}

// ============ fused score + online-softmax + aggregate =====================
// 16 lanes per node (LPT-sorted order), batch-8 gather pipelining.

__device__ __forceinline__ void agg_step(ushort8_t hv, const float* xrv,
        const float* atv, float& m, float& den, float* ac) {
  float v[8];
#pragma unroll
  for (int j = 0; j < 8; ++j) v[j] = bf2f(hv[j]);
  float p = 0.f;
#pragma unroll
  for (int j = 0; j < 8; ++j) {
    float tt = v[j] + xrv[j];
    tt = tt > 0.f ? tt : NEG_SLOPE * tt;
    p += tt * atv[j];
  }
  p += __shfl_xor(p, 1);
  p += __shfl_xor(p, 2);
  p += __shfl_xor(p, 4);
  p += __shfl_xor(p, 8);
  if (p > m) {
    float sc = __expf(m - p);
    den *= sc;
#pragma unroll
    for (int j = 0; j < 8; ++j) ac[j] *= sc;
    m = p;
  }
  float a = __expf(p - m);
  den += a;
#pragma unroll
  for (int j = 0; j < 8; ++j) ac[j] += a * v[j];
}

__global__ __launch_bounds__(256) void k_agg(const unsigned short* __restrict__ xlb,
        const unsigned short* __restrict__ xrb, const int* __restrict__ col_src,
        const int* __restrict__ row_ptr, const int* __restrict__ node_order,
        const float* __restrict__ att, float* __restrict__ out, int n) {
  int g = blockIdx.x * 16 + (threadIdx.x >> 4);
  if (g >= n) return;
  int node = node_order[g];
  int lane = threadIdx.x & 15;
  int ro = lane * 2;
  ushort8_t hr = ((const ushort8_t*)(xrb + (size_t)node * D))[lane];
  float xrv[8];
#pragma unroll
  for (int j = 0; j < 8; ++j) xrv[j] = bf2f(hr[j]);
  float4 at0 = ((const float4*)att)[ro];
  float4 at1 = ((const float4*)att)[ro + 1];
  float atv[8] = {at0.x, at0.y, at0.z, at0.w, at1.x, at1.y, at1.z, at1.w};

  int k0 = row_ptr[node], k1 = row_ptr[node + 1];
  float m = -1e30f, den = 0.f;
  float ac[8];
#pragma unroll
  for (int j = 0; j < 8; ++j) ac[j] = 0.f;

  const ushort8_t* xl8 = (const ushort8_t*)xlb;
  int k = k0;
  for (; k + 8 <= k1; k += 8) {
    int s0 = col_src[k],     s1 = col_src[k + 1], s2 = col_src[k + 2], s3 = col_src[k + 3];
    int s4 = col_src[k + 4], s5 = col_src[k + 5], s6 = col_src[k + 6], s7 = col_src[k + 7];
    ushort8_t h0 = xl8[(size_t)s0 * 16 + lane];
    ushort8_t h1 = xl8[(size_t)s1 * 16 + lane];
    ushort8_t h2 = xl8[(size_t)s2 * 16 + lane];
    ushort8_t h3 = xl8[(size_t)s3 * 16 + lane];
    ushort8_t h4 = xl8[(size_t)s4 * 16 + lane];
    ushort8_t h5 = xl8[(size_t)s5 * 16 + lane];
    ushort8_t h6 = xl8[(size_t)s6 * 16 + lane];
    ushort8_t h7 = xl8[(size_t)s7 * 16 + lane];
    agg_step(h0, xrv, atv, m, den, ac);
    agg_step(h1, xrv, atv, m, den, ac);
    agg_step(h2, xrv, atv, m, den, ac);
    agg_step(h3, xrv, atv, m, den, ac);
    agg_step(h4, xrv, atv, m, den, ac);
    agg_step(h5, xrv, atv, m, den, ac);
    agg_step(h6, xrv, atv, m, den, ac);
    agg_step(h7, xrv, atv, m, den, ac);
  }
  if (k + 4 <= k1) {
    int s0 = col_src[k], s1 = col_src[k + 1], s2 = col_src[k + 2], s3 = col_src[k + 3];
    ushort8_t h0 = xl8[(size_t)s0 * 16 + lane];
    ushort8_t h1 = xl8[(size_t)s1 * 16 + lane];
    ushort8_t h2 = xl8[(size_t)s2 * 16 + lane];
    ushort8_t h3 = xl8[(size_t)s3 * 16 + lane];
    agg_step(h0, xrv, atv, m, den, ac);
    agg_step(h1, xrv, atv, m, den, ac);
    agg_step(h2, xrv, atv, m, den, ac);
    agg_step(h3, xrv, atv, m, den, ac);
    k += 4;
  }
  for (; k < k1; ++k) {
    int s = col_src[k];
    ushort8_t h = xl8[(size_t)s * 16 + lane];
    agg_step(h, xrv, atv, m, den, ac);
  }

  float inv = 1.f / (den + 1e-16f);
  float4* o4 = (float4*)out;
  o4[(size_t)node * 32 + ro]     = make_float4(ac[0] * inv, ac[1] * inv, ac[2] * inv, ac[3] * inv);
  o4[(size_t)node * 32 + ro + 1] = make_float4(ac[4] * inv, ac[5] * inv, ac[6] * inv, ac[7] * inv);
}

// ============ BatchNorm + GELU =============================================
// Stage 1: per-block (80 rows) partial sum/sumsq, no atomics.
__global__ __launch_bounds__(256) void k_bn_part(const float* __restrict__ agg,
        float* __restrict__ partial) {
  __shared__ float4 lsum[256], lsq[256];
  int t = threadIdx.x;
  int cg = t & 31, rg = t >> 5;
  int rbase = blockIdx.x * BN_ROWS;
  float4 s = make_float4(0.f, 0.f, 0.f, 0.f);
  float4 q = make_float4(0.f, 0.f, 0.f, 0.f);
#pragma unroll
  for (int p = 0; p < BN_ROWS / 8; ++p) {
    int r = rbase + p * 8 + rg;
    float4 v = ((const float4*)agg)[(size_t)r * 32 + cg];
    s.x += v.x; s.y += v.y; s.z += v.z; s.w += v.w;
    q.x += v.x * v.x; q.y += v.y * v.y; q.z += v.z * v.z; q.w += v.w * v.w;
  }
  lsum[t] = s; lsq[t] = q;
  __syncthreads();
  if (t < 32) {
    float4 a = lsum[t];
#pragma unroll
    for (int j = 1; j < 8; ++j) {
      float4 b = lsum[j * 32 + t];
      a.x += b.x; a.y += b.y; a.z += b.z; a.w += b.w;
    }
    ((float4*)(partial + (size_t)blockIdx.x * 256))[t] = a;
  } else if (t < 64) {
    int c = t - 32;
    float4 a = lsq[c];
#pragma unroll
    for (int j = 1; j < 8; ++j) {
      float4 b = lsq[j * 32 + c];
      a.x += b.x; a.y += b.y; a.z += b.z; a.w += b.w;
    }
    ((float4*)(partial + (size_t)blockIdx.x * 256 + 128))[c] = a;
  }
}

// Stage 2: reduce 625 partial records, emit scale/shift directly.
__global__ void k_bn_fin2(const float* __restrict__ partial,
        const float* __restrict__ gamma, const float* __restrict__ beta,
        float* __restrict__ ss, float inv_n) {
  __shared__ float lds[256];
  int t = threadIdx.x;
  float acc = 0.f;
  for (int b = 0; b < BN_NB; ++b) acc += partial[(size_t)b * 256 + t];
  lds[t] = acc;
  __syncthreads();
  if (t < 128) {
    float mu = lds[t] * inv_n;
    float var = lds[128 + t] * inv_n - mu * mu;
    float rs = rsqrtf(var + BN_EPS);
    float sc = gamma[t] * rs;
    ss[t] = sc;
    ss[128 + t] = beta[t] - mu * sc;
  }
}

// writes f32 result AND bf16 mirror (next layer's GEMM input)
__global__ __launch_bounds__(256) void k_bn_apply(const float* __restrict__ agg,
        const float* __restrict__ ss, float* __restrict__ xo,
        unsigned short* __restrict__ xbo, int total4) {
  int i = blockIdx.x * 256 + threadIdx.x;
  if (i >= total4) return;
  float4 v = ((const float4*)agg)[i];
  int c4 = i & (D / 4 - 1);
  float4 sc = ((const float4*)ss)[c4];
  float4 sh = ((const float4*)ss)[D / 4 + c4];
  float y0 = sc.x * v.x + sh.x;
  float y1 = sc.y * v.y + sh.y;
  float y2 = sc.z * v.z + sh.z;
  float y3 = sc.w * v.w + sh.w;
  float4 g;
  g.x = 0.5f * y0 * (1.f + erff(y0 * 0.70710678118654752f));
  g.y = 0.5f * y1 * (1.f + erff(y1 * 0.70710678118654752f));
  g.z = 0.5f * y2 * (1.f + erff(y2 * 0.70710678118654752f));
  g.w = 0.5f * y3 * (1.f + erff(y3 * 0.70710678118654752f));
  ((float4*)xo)[i] = g;
  uint2 pk;
  pk.x = (unsigned)f2bf(g.x) | ((unsigned)f2bf(g.y) << 16);
  pk.y = (unsigned)f2bf(g.z) | ((unsigned)f2bf(g.w) << 16);
  ((uint2*)xbo)[i] = pk;
}

// ===========================================================================

extern "C" void kernel_launch(void* const* d_in, const int* in_sizes, int n_in,
                              void* d_out, int out_size, void* d_ws, size_t ws_size,
                              hipStream_t stream) {
  const float* x0    = (const float*)d_in[0];
  const int*   ei    = (const int*)d_in[1];
  const float* Wl    = (const float*)d_in[2];
  const float* Wr    = (const float*)d_in[3];
  const float* att   = (const float*)d_in[4];
  // d_in[5] = bias: cancelled exactly by BatchNorm mean-subtraction; unused.
  const float* gamma = (const float*)d_in[6];
  const float* beta  = (const float*)d_in[7];
  float* out = (float*)d_out;

  float* ws = (float*)d_ws;
  unsigned short* xb  = (unsigned short*)ws;              // [N][128] bf16
  unsigned short* xlb = (unsigned short*)(ws + 3200000);  // [N][128] bf16
  unsigned short* xrb = (unsigned short*)(ws + 6400000);  // [N][128] bf16
  int*   col_src    = (int*)(ws + 9600000);       //   800,000
  int*   rank       = (int*)(ws + 10400000);      //   800,000
  int*   row_ptr    = (int*)(ws + 11200000);      //    50,001
  int*   counts     = (int*)(ws + 11250004);      // COUNTS_PAD (53,248)
  int*   node_order = (int*)(ws + 11303252);      //    50,000
  float* partial    = ws + 11353252;              //   160,000 (625 x 256)
  float* ss         = ws + 11513252;              //       256
  unsigned short* wt = (unsigned short*)(ws + 11513508);  // [3][2][128][128] bf16

  const int* src = ei;
  const int* dst = ei + NEDGES;

  // ---- one-time: CSR build + LPT degree sort + converts ----
  hipMemsetAsync(counts, 0, COUNTS_PAD * sizeof(int), stream);
  k_rank<<<(NEDGES + 255) / 256, 256, 0, stream>>>(dst, counts, rank, NEDGES);
  k_scan_all<<<1, SCAN_THREADS, 0, stream>>>(counts, row_ptr, NNODES);
  k_place<<<(NEDGES + 255) / 256, 256, 0, stream>>>(src, dst, rank, row_ptr, col_src, NEDGES);
  k_deg_sort<<<1, DEG_BINS, 0, stream>>>(row_ptr, node_order, NNODES);
  k_cvt_w<<<6, 256, 0, stream>>>(Wl, Wr, wt);
  k_cvt_x<<<(NNODES * (D / 8) + 255) / 256, 256, 0, stream>>>(x0, xb, NNODES * (D / 8));

  dim3 ggrid((NNODES + 127) / 128, 2);

  for (int l = 0; l < 3; ++l) {
    k_gemm<<<ggrid, 256, 0, stream>>>(xb, wt + (size_t)l * 2 * D * D, xlb, xrb, NNODES);

    // d_out is dead as an input after k_gemm -> safe to overwrite with agg.
    k_agg<<<(NNODES + 15) / 16, 256, 0, stream>>>(xlb, xrb, col_src, row_ptr,
                                                  node_order, att + l * D, out, NNODES);

    k_bn_part<<<BN_NB, 256, 0, stream>>>(out, partial);
    k_bn_fin2<<<1, 256, 0, stream>>>(partial, gamma + l * D, beta + l * D, ss, 1.0f / NNODES);
    k_bn_apply<<<(NNODES * (D / 4) + 255) / 256, 256, 0, stream>>>(out, ss, out, xb,
                                                                   NNODES * (D / 4));
  }
}

// Round 16
// 406.430 us; speedup vs baseline: 1.9180x; 1.1975x over previous
//
#include <hip/hip_runtime.h>
#include <math.h>

#define NNODES 50000
#define NEDGES 800000
#define D 128
#define NEG_SLOPE 0.2f
#define BN_EPS 1e-5f
#define SCAN_THREADS 1024
#define WAVE_REGION 3328                      // 52 elems x 64 lanes
#define COUNTS_PAD (16 * WAVE_REGION)         // 53248 >= 50000
#define DEG_BINS 1024
#define BN_NB 625                             // 625 blocks x 80 rows = 50000
#define BN_ROWS 80

typedef __attribute__((ext_vector_type(8))) unsigned short ushort8_t;
typedef __attribute__((ext_vector_type(8))) short bf16x8;
typedef __attribute__((ext_vector_type(4))) float f32x4;

// RNE float -> bf16
__device__ __forceinline__ unsigned short f2bf(float x) {
  unsigned u = __float_as_uint(x);
  u += 0x7fffu + ((u >> 16) & 1u);
  return (unsigned short)(u >> 16);
}
__device__ __forceinline__ float bf2f(unsigned short h) {
  return __uint_as_float((unsigned)h << 16);
}

// ============ CSR build (once per call) ====================================
// rank[e] = position of edge e among edges with the same dst (atomic order)
__global__ __launch_bounds__(256) void k_rank(const int* __restrict__ dst,
        int* __restrict__ counts, int* __restrict__ rank, int E) {
  int e = blockIdx.x * 256 + threadIdx.x;
  if (e < E) rank[e] = atomicAdd(&counts[dst[e]], 1);
}

// Single-WG coalesced scan: wave w owns contiguous region of 3328 counts.
__global__ __launch_bounds__(1024) void k_scan_all(const int* __restrict__ counts,
        int* __restrict__ row_ptr, int n) {
  __shared__ int wtot[16];
  int t = threadIdx.x;
  int lane = t & 63, w = t >> 6;
  int rb = w * WAVE_REGION;
  int tot = 0;
  for (int j = 0; j < 52; ++j) tot += counts[rb + j * 64 + lane];
#pragma unroll
  for (int d = 1; d < 64; d <<= 1) tot += __shfl_xor(tot, d);
  if (lane == 0) wtot[w] = tot;
  __syncthreads();
  int wbase = 0;
#pragma unroll
  for (int i = 0; i < 16; ++i) wbase += (i < w) ? wtot[i] : 0;
  int running = wbase;
  for (int j = 0; j < 52; ++j) {
    int idx = rb + j * 64 + lane;
    int v = counts[idx];
    int incl = v;
#pragma unroll
    for (int d = 1; d < 64; d <<= 1) {
      int u = __shfl_up(incl, d);
      if (lane >= d) incl += u;
    }
    if (idx < n) row_ptr[idx + 1] = running + incl;
    running += __shfl(incl, 63);
  }
  if (t == 0) row_ptr[0] = 0;
}

// atomic-free placement: slot = row_ptr[dst] + rank
__global__ __launch_bounds__(256) void k_place(const int* __restrict__ src,
        const int* __restrict__ dst, const int* __restrict__ rank,
        const int* __restrict__ row_ptr, int* __restrict__ col_src, int E) {
  int e = blockIdx.x * 256 + threadIdx.x;
  if (e >= E) return;
  col_src[row_ptr[dst[e]] + rank[e]] = src[e];
}

// ---- degree counting-sort, single WG, LDS bins, LPT (descending) order ----
__global__ __launch_bounds__(1024) void k_deg_sort(const int* __restrict__ row_ptr,
        int* __restrict__ node_order, int n) {
  __shared__ int hist[DEG_BINS];
  int t = threadIdx.x;
  hist[t] = 0;
  __syncthreads();
  for (int i = t; i < n; i += 1024) {
    int d = row_ptr[i + 1] - row_ptr[i];
    if (d > DEG_BINS - 1) d = DEG_BINS - 1;
    int bin = (DEG_BINS - 1) - d;          // descending
    atomicAdd(&hist[bin], 1);
  }
  __syncthreads();
  int v = hist[t];
  for (int off = 1; off < DEG_BINS; off <<= 1) {
    int u = (t >= off) ? hist[t - off] : 0;
    __syncthreads();
    hist[t] += u;
    __syncthreads();
  }
  int excl = hist[t] - v;
  __syncthreads();
  hist[t] = excl;          // cursor base per bin
  __syncthreads();
  for (int i = t; i < n; i += 1024) {
    int d = row_ptr[i + 1] - row_ptr[i];
    if (d > DEG_BINS - 1) d = DEG_BINS - 1;
    int bin = (DEG_BINS - 1) - d;
    int pos = atomicAdd(&hist[bin], 1);
    node_order[pos] = i;
  }
}

// ============ one-time converts ============================================

__global__ __launch_bounds__(256) void k_cvt_x(const float* __restrict__ x,
        unsigned short* __restrict__ xb, int total8) {
  int i = blockIdx.x * 256 + threadIdx.x;
  if (i >= total8) return;
  float4 a = ((const float4*)x)[2 * i];
  float4 b = ((const float4*)x)[2 * i + 1];
  uint4 pk;
  pk.x = (unsigned)f2bf(a.x) | ((unsigned)f2bf(a.y) << 16);
  pk.y = (unsigned)f2bf(a.z) | ((unsigned)f2bf(a.w) << 16);
  pk.z = (unsigned)f2bf(b.x) | ((unsigned)f2bf(b.y) << 16);
  pk.w = (unsigned)f2bf(b.z) | ((unsigned)f2bf(b.w) << 16);
  ((uint4*)xb)[i] = pk;
}

// W[l,s][k][col] f32 -> wt[(2l+s)][col][k] bf16 (transposed, K-contiguous)
__global__ void k_cvt_w(const float* __restrict__ Wl, const float* __restrict__ Wr,
        unsigned short* __restrict__ wt) {
  int ls = blockIdx.x;           // 0..5 = layer*2 + side
  int l = ls >> 1, s = ls & 1;
  const float* W = (s ? Wr : Wl) + l * D * D;
  unsigned short* o = wt + ls * D * D;
  for (int it = 0; it < 64; ++it) {
    int idx = it * 256 + threadIdx.x;
    int k = idx >> 7, c = idx & 127;
    o[c * D + k] = f2bf(W[idx]);
  }
}

// ============ GEMM: bf16 MFMA 16x16x32 =====================================
__global__ __launch_bounds__(256) void k_gemm(const unsigned short* __restrict__ xb,
        const unsigned short* __restrict__ wt,   // this layer: [2][128 col][128 k]
        unsigned short* __restrict__ xlb, unsigned short* __restrict__ xrb, int n) {
  __shared__ unsigned short xs[128 * 128];   // 32 KB
  const int t = threadIdx.x;
  const int row0 = blockIdx.x * 128;
  const unsigned short* __restrict__ W = wt + (size_t)blockIdx.y * (D * D);
  unsigned short* __restrict__ outp = blockIdx.y ? xrb : xlb;

#pragma unroll
  for (int i = 0; i < 8; ++i) {
    int ci = i * 256 + t;          // 16B-chunk index 0..2047
    int lr = ci >> 4, p = ci & 15;
    int grow = row0 + lr;
    if (grow >= n) grow = n - 1;   // clamped rows are never stored
    int gp = p ^ (lr & 7);
    uint4 v = *(const uint4*)(xb + (size_t)grow * D + gp * 8);
    *(uint4*)((char*)xs + ci * 16) = v;
  }
  __syncthreads();

  const int lane = t & 63, wv = t >> 6;
  const int colg = lane & 15, kg = lane >> 4;

  f32x4 acc[2][8];
#pragma unroll
  for (int rr = 0; rr < 2; ++rr)
#pragma unroll
    for (int cc = 0; cc < 8; ++cc) acc[rr][cc] = (f32x4)(0.f);

#pragma unroll
  for (int ks = 0; ks < 4; ++ks) {
    bf16x8 a[2], b[8];
#pragma unroll
    for (int rr = 0; rr < 2; ++rr) {
      int lr = wv * 32 + rr * 16 + colg;
      int byte = (lr * 256 + ks * 64 + kg * 16) ^ ((lr & 7) << 4);
      a[rr] = *(const bf16x8*)((const char*)xs + byte);
    }
#pragma unroll
    for (int cc = 0; cc < 8; ++cc) {
      int col = cc * 16 + colg;
      b[cc] = *(const bf16x8*)(W + (size_t)col * D + ks * 32 + kg * 8);
    }
#pragma unroll
    for (int rr = 0; rr < 2; ++rr)
#pragma unroll
      for (int cc = 0; cc < 8; ++cc)
        acc[rr][cc] = __builtin_amdgcn_mfma_f32_16x16x32_bf16(a[rr], b[cc], acc[rr][cc], 0, 0, 0);
  }

#pragma unroll
  for (int rr = 0; rr < 2; ++rr) {
    int rbase = row0 + wv * 32 + rr * 16 + kg * 4;
#pragma unroll
    for (int cc = 0; cc < 8; ++cc) {
      int col = cc * 16 + colg;
      f32x4 v = acc[rr][cc];
#pragma unroll
      for (int r = 0; r < 4; ++r) {
        int grow = rbase + r;
        if (grow < n) outp[(size_t)grow * D + col] = f2bf(v[r]);
      }
    }
  }
}

// ============ fused score + online-softmax + aggregate =====================
// 16 lanes per node (LPT-sorted order), batch-8 gather pipelining.

__device__ __forceinline__ void agg_step(ushort8_t hv, const float* xrv,
        const float* atv, float& m, float& den, float* ac) {
  float v[8];
#pragma unroll
  for (int j = 0; j < 8; ++j) v[j] = bf2f(hv[j]);
  float p = 0.f;
#pragma unroll
  for (int j = 0; j < 8; ++j) {
    float tt = v[j] + xrv[j];
    tt = tt > 0.f ? tt : NEG_SLOPE * tt;
    p += tt * atv[j];
  }
  p += __shfl_xor(p, 1);
  p += __shfl_xor(p, 2);
  p += __shfl_xor(p, 4);
  p += __shfl_xor(p, 8);
  if (p > m) {
    float sc = __expf(m - p);
    den *= sc;
#pragma unroll
    for (int j = 0; j < 8; ++j) ac[j] *= sc;
    m = p;
  }
  float a = __expf(p - m);
  den += a;
#pragma unroll
  for (int j = 0; j < 8; ++j) ac[j] += a * v[j];
}

__global__ __launch_bounds__(256) void k_agg(const unsigned short* __restrict__ xlb,
        const unsigned short* __restrict__ xrb, const int* __restrict__ col_src,
        const int* __restrict__ row_ptr, const int* __restrict__ node_order,
        const float* __restrict__ att, float* __restrict__ out, int n) {
  int g = blockIdx.x * 16 + (threadIdx.x >> 4);
  if (g >= n) return;
  int node = node_order[g];
  int lane = threadIdx.x & 15;
  int ro = lane * 2;
  ushort8_t hr = ((const ushort8_t*)(xrb + (size_t)node * D))[lane];
  float xrv[8];
#pragma unroll
  for (int j = 0; j < 8; ++j) xrv[j] = bf2f(hr[j]);
  float4 at0 = ((const float4*)att)[ro];
  float4 at1 = ((const float4*)att)[ro + 1];
  float atv[8] = {at0.x, at0.y, at0.z, at0.w, at1.x, at1.y, at1.z, at1.w};

  int k0 = row_ptr[node], k1 = row_ptr[node + 1];
  float m = -1e30f, den = 0.f;
  float ac[8];
#pragma unroll
  for (int j = 0; j < 8; ++j) ac[j] = 0.f;

  const ushort8_t* xl8 = (const ushort8_t*)xlb;
  int k = k0;
  for (; k + 8 <= k1; k += 8) {
    int s0 = col_src[k],     s1 = col_src[k + 1], s2 = col_src[k + 2], s3 = col_src[k + 3];
    int s4 = col_src[k + 4], s5 = col_src[k + 5], s6 = col_src[k + 6], s7 = col_src[k + 7];
    ushort8_t h0 = xl8[(size_t)s0 * 16 + lane];
    ushort8_t h1 = xl8[(size_t)s1 * 16 + lane];
    ushort8_t h2 = xl8[(size_t)s2 * 16 + lane];
    ushort8_t h3 = xl8[(size_t)s3 * 16 + lane];
    ushort8_t h4 = xl8[(size_t)s4 * 16 + lane];
    ushort8_t h5 = xl8[(size_t)s5 * 16 + lane];
    ushort8_t h6 = xl8[(size_t)s6 * 16 + lane];
    ushort8_t h7 = xl8[(size_t)s7 * 16 + lane];
    agg_step(h0, xrv, atv, m, den, ac);
    agg_step(h1, xrv, atv, m, den, ac);
    agg_step(h2, xrv, atv, m, den, ac);
    agg_step(h3, xrv, atv, m, den, ac);
    agg_step(h4, xrv, atv, m, den, ac);
    agg_step(h5, xrv, atv, m, den, ac);
    agg_step(h6, xrv, atv, m, den, ac);
    agg_step(h7, xrv, atv, m, den, ac);
  }
  if (k + 4 <= k1) {
    int s0 = col_src[k], s1 = col_src[k + 1], s2 = col_src[k + 2], s3 = col_src[k + 3];
    ushort8_t h0 = xl8[(size_t)s0 * 16 + lane];
    ushort8_t h1 = xl8[(size_t)s1 * 16 + lane];
    ushort8_t h2 = xl8[(size_t)s2 * 16 + lane];
    ushort8_t h3 = xl8[(size_t)s3 * 16 + lane];
    agg_step(h0, xrv, atv, m, den, ac);
    agg_step(h1, xrv, atv, m, den, ac);
    agg_step(h2, xrv, atv, m, den, ac);
    agg_step(h3, xrv, atv, m, den, ac);
    k += 4;
  }
  for (; k < k1; ++k) {
    int s = col_src[k];
    ushort8_t h = xl8[(size_t)s * 16 + lane];
    agg_step(h, xrv, atv, m, den, ac);
  }

  float inv = 1.f / (den + 1e-16f);
  float4* o4 = (float4*)out;
  o4[(size_t)node * 32 + ro]     = make_float4(ac[0] * inv, ac[1] * inv, ac[2] * inv, ac[3] * inv);
  o4[(size_t)node * 32 + ro + 1] = make_float4(ac[4] * inv, ac[5] * inv, ac[6] * inv, ac[7] * inv);
}

// ============ BatchNorm + GELU =============================================
// Stage 1: per-block (80 rows) partial sum/sumsq, no atomics.
__global__ __launch_bounds__(256) void k_bn_part(const float* __restrict__ agg,
        float* __restrict__ partial) {
  __shared__ float4 lsum[256], lsq[256];
  int t = threadIdx.x;
  int cg = t & 31, rg = t >> 5;
  int rbase = blockIdx.x * BN_ROWS;
  float4 s = make_float4(0.f, 0.f, 0.f, 0.f);
  float4 q = make_float4(0.f, 0.f, 0.f, 0.f);
#pragma unroll
  for (int p = 0; p < BN_ROWS / 8; ++p) {
    int r = rbase + p * 8 + rg;
    float4 v = ((const float4*)agg)[(size_t)r * 32 + cg];
    s.x += v.x; s.y += v.y; s.z += v.z; s.w += v.w;
    q.x += v.x * v.x; q.y += v.y * v.y; q.z += v.z * v.z; q.w += v.w * v.w;
  }
  lsum[t] = s; lsq[t] = q;
  __syncthreads();
  if (t < 32) {
    float4 a = lsum[t];
#pragma unroll
    for (int j = 1; j < 8; ++j) {
      float4 b = lsum[j * 32 + t];
      a.x += b.x; a.y += b.y; a.z += b.z; a.w += b.w;
    }
    ((float4*)(partial + (size_t)blockIdx.x * 256))[t] = a;
  } else if (t < 64) {
    int c = t - 32;
    float4 a = lsq[c];
#pragma unroll
    for (int j = 1; j < 8; ++j) {
      float4 b = lsq[j * 32 + c];
      a.x += b.x; a.y += b.y; a.z += b.z; a.w += b.w;
    }
    ((float4*)(partial + (size_t)blockIdx.x * 256 + 128))[c] = a;
  }
}

// Stage 2: 1024 threads, 4-way split over the 625 records, 4 independent
// accumulators each (round-15 lesson: 256-thread single-accumulator chain
// ran at 1 load in flight = 41us for 640KB).
__global__ __launch_bounds__(1024) void k_bn_fin2(const float* __restrict__ partial,
        const float* __restrict__ gamma, const float* __restrict__ beta,
        float* __restrict__ ss, float inv_n) {
  __shared__ float red[4][256];
  int t = threadIdx.x;
  int c = t & 255, q = t >> 8;           // channel-slot, quarter
  int start = (BN_NB * q) >> 2, end = (BN_NB * (q + 1)) >> 2;
  float a0 = 0.f, a1 = 0.f, a2 = 0.f, a3 = 0.f;
  int b = start;
  for (; b + 4 <= end; b += 4) {
    a0 += partial[(size_t)(b + 0) * 256 + c];
    a1 += partial[(size_t)(b + 1) * 256 + c];
    a2 += partial[(size_t)(b + 2) * 256 + c];
    a3 += partial[(size_t)(b + 3) * 256 + c];
  }
  for (; b < end; ++b) a0 += partial[(size_t)b * 256 + c];
  red[q][c] = (a0 + a1) + (a2 + a3);
  __syncthreads();
  if (t < 128) {
    float s  = (red[0][t] + red[1][t]) + (red[2][t] + red[3][t]);
    float sq = (red[0][128 + t] + red[1][128 + t]) + (red[2][128 + t] + red[3][128 + t]);
    float mu = s * inv_n;
    float var = sq * inv_n - mu * mu;
    float rs = rsqrtf(var + BN_EPS);
    float sc = gamma[t] * rs;
    ss[t] = sc;
    ss[128 + t] = beta[t] - mu * sc;
  }
}

// writes f32 result AND bf16 mirror (next layer's GEMM input)
__global__ __launch_bounds__(256) void k_bn_apply(const float* __restrict__ agg,
        const float* __restrict__ ss, float* __restrict__ xo,
        unsigned short* __restrict__ xbo, int total4) {
  int i = blockIdx.x * 256 + threadIdx.x;
  if (i >= total4) return;
  float4 v = ((const float4*)agg)[i];
  int c4 = i & (D / 4 - 1);
  float4 sc = ((const float4*)ss)[c4];
  float4 sh = ((const float4*)ss)[D / 4 + c4];
  float y0 = sc.x * v.x + sh.x;
  float y1 = sc.y * v.y + sh.y;
  float y2 = sc.z * v.z + sh.z;
  float y3 = sc.w * v.w + sh.w;
  float4 g;
  g.x = 0.5f * y0 * (1.f + erff(y0 * 0.70710678118654752f));
  g.y = 0.5f * y1 * (1.f + erff(y1 * 0.70710678118654752f));
  g.z = 0.5f * y2 * (1.f + erff(y2 * 0.70710678118654752f));
  g.w = 0.5f * y3 * (1.f + erff(y3 * 0.70710678118654752f));
  ((float4*)xo)[i] = g;
  uint2 pk;
  pk.x = (unsigned)f2bf(g.x) | ((unsigned)f2bf(g.y) << 16);
  pk.y = (unsigned)f2bf(g.z) | ((unsigned)f2bf(g.w) << 16);
  ((uint2*)xbo)[i] = pk;
}

// ===========================================================================

extern "C" void kernel_launch(void* const* d_in, const int* in_sizes, int n_in,
                              void* d_out, int out_size, void* d_ws, size_t ws_size,
                              hipStream_t stream) {
  const float* x0    = (const float*)d_in[0];
  const int*   ei    = (const int*)d_in[1];
  const float* Wl    = (const float*)d_in[2];
  const float* Wr    = (const float*)d_in[3];
  const float* att   = (const float*)d_in[4];
  // d_in[5] = bias: cancelled exactly by BatchNorm mean-subtraction; unused.
  const float* gamma = (const float*)d_in[6];
  const float* beta  = (const float*)d_in[7];
  float* out = (float*)d_out;

  float* ws = (float*)d_ws;
  unsigned short* xb  = (unsigned short*)ws;              // [N][128] bf16
  unsigned short* xlb = (unsigned short*)(ws + 3200000);  // [N][128] bf16
  unsigned short* xrb = (unsigned short*)(ws + 6400000);  // [N][128] bf16
  int*   col_src    = (int*)(ws + 9600000);       //   800,000
  int*   rank       = (int*)(ws + 10400000);      //   800,000
  int*   row_ptr    = (int*)(ws + 11200000);      //    50,001
  int*   counts     = (int*)(ws + 11250004);      // COUNTS_PAD (53,248)
  int*   node_order = (int*)(ws + 11303252);      //    50,000
  float* partial    = ws + 11353252;              //   160,000 (625 x 256)
  float* ss         = ws + 11513252;              //       256
  unsigned short* wt = (unsigned short*)(ws + 11513508);  // [3][2][128][128] bf16

  const int* src = ei;
  const int* dst = ei + NEDGES;

  // ---- one-time: CSR build + LPT degree sort + converts ----
  hipMemsetAsync(counts, 0, COUNTS_PAD * sizeof(int), stream);
  k_rank<<<(NEDGES + 255) / 256, 256, 0, stream>>>(dst, counts, rank, NEDGES);
  k_scan_all<<<1, SCAN_THREADS, 0, stream>>>(counts, row_ptr, NNODES);
  k_place<<<(NEDGES + 255) / 256, 256, 0, stream>>>(src, dst, rank, row_ptr, col_src, NEDGES);
  k_deg_sort<<<1, DEG_BINS, 0, stream>>>(row_ptr, node_order, NNODES);
  k_cvt_w<<<6, 256, 0, stream>>>(Wl, Wr, wt);
  k_cvt_x<<<(NNODES * (D / 8) + 255) / 256, 256, 0, stream>>>(x0, xb, NNODES * (D / 8));

  dim3 ggrid((NNODES + 127) / 128, 2);

  for (int l = 0; l < 3; ++l) {
    k_gemm<<<ggrid, 256, 0, stream>>>(xb, wt + (size_t)l * 2 * D * D, xlb, xrb, NNODES);

    // d_out is dead as an input after k_gemm -> safe to overwrite with agg.
    k_agg<<<(NNODES + 15) / 16, 256, 0, stream>>>(xlb, xrb, col_src, row_ptr,
                                                  node_order, att + l * D, out, NNODES);

    k_bn_part<<<BN_NB, 256, 0, stream>>>(out, partial);
    k_bn_fin2<<<1, 1024, 0, stream>>>(partial, gamma + l * D, beta + l * D, ss, 1.0f / NNODES);
    k_bn_apply<<<(NNODES * (D / 4) + 255) / 256, 256, 0, stream>>>(out, ss, out, xb,
                                                                   NNODES * (D / 4));
  }
}

// Round 17
// 347.007 us; speedup vs baseline: 2.2465x; 1.1712x over previous
//
#include <hip/hip_runtime.h>
#include <math.h>

#define NNODES 50000
#define NEDGES 800000
#define D 128
#define NEG_SLOPE 0.2f
#define BN_EPS 1e-5f
#define SCAN_THREADS 1024
#define WAVE_REGION 3328                      // 52 elems x 64 lanes
#define COUNTS_PAD (16 * WAVE_REGION)         // 53248 >= 50000
#define DEG_BINS 1024
#define SUM_SLOTS 64                          // 3125 agg blocks -> ~49 adds/slot

typedef __attribute__((ext_vector_type(8))) unsigned short ushort8_t;
typedef __attribute__((ext_vector_type(8))) short bf16x8;
typedef __attribute__((ext_vector_type(4))) float f32x4;

// RNE float -> bf16
__device__ __forceinline__ unsigned short f2bf(float x) {
  unsigned u = __float_as_uint(x);
  u += 0x7fffu + ((u >> 16) & 1u);
  return (unsigned short)(u >> 16);
}
__device__ __forceinline__ float bf2f(unsigned short h) {
  return __uint_as_float((unsigned)h << 16);
}

// ============ CSR build (once per call) ====================================
// rank[e] = position of edge e among edges with the same dst (atomic order)
__global__ __launch_bounds__(256) void k_rank(const int* __restrict__ dst,
        int* __restrict__ counts, int* __restrict__ rank, int E) {
  int e = blockIdx.x * 256 + threadIdx.x;
  if (e < E) rank[e] = atomicAdd(&counts[dst[e]], 1);
}

// Single-WG: coalesced scan (counts -> row_ptr) THEN LPT degree counting-sort
// (degree comes straight from counts). Two phases, one dispatch.
__global__ __launch_bounds__(1024) void k_scan_sort(const int* __restrict__ counts,
        int* __restrict__ row_ptr, int* __restrict__ node_order, int n) {
  __shared__ int wtot[16];
  __shared__ int hist[DEG_BINS];
  int t = threadIdx.x;
  int lane = t & 63, w = t >> 6;
  int rb = w * WAVE_REGION;
  // ---- phase 1: scan ----
  int tot = 0;
  for (int j = 0; j < 52; ++j) tot += counts[rb + j * 64 + lane];
#pragma unroll
  for (int d = 1; d < 64; d <<= 1) tot += __shfl_xor(tot, d);
  if (lane == 0) wtot[w] = tot;
  __syncthreads();
  int wbase = 0;
#pragma unroll
  for (int i = 0; i < 16; ++i) wbase += (i < w) ? wtot[i] : 0;
  int running = wbase;
  for (int j = 0; j < 52; ++j) {
    int idx = rb + j * 64 + lane;
    int v = counts[idx];
    int incl = v;
#pragma unroll
    for (int d = 1; d < 64; d <<= 1) {
      int u = __shfl_up(incl, d);
      if (lane >= d) incl += u;
    }
    if (idx < n) row_ptr[idx + 1] = running + incl;
    running += __shfl(incl, 63);
  }
  if (t == 0) row_ptr[0] = 0;
  // ---- phase 2: LPT degree sort (descending; LDS bins) ----
  hist[t] = 0;
  __syncthreads();
  for (int i = t; i < n; i += 1024) {
    int d = counts[i];
    if (d > DEG_BINS - 1) d = DEG_BINS - 1;
    atomicAdd(&hist[(DEG_BINS - 1) - d], 1);
  }
  __syncthreads();
  int v = hist[t];
  for (int off = 1; off < DEG_BINS; off <<= 1) {
    int u = (t >= off) ? hist[t - off] : 0;
    __syncthreads();
    hist[t] += u;
    __syncthreads();
  }
  int excl = hist[t] - v;
  __syncthreads();
  hist[t] = excl;          // cursor base per bin
  __syncthreads();
  for (int i = t; i < n; i += 1024) {
    int d = counts[i];
    if (d > DEG_BINS - 1) d = DEG_BINS - 1;
    int pos = atomicAdd(&hist[(DEG_BINS - 1) - d], 1);
    node_order[pos] = i;
  }
}

// atomic-free placement: slot = row_ptr[dst] + rank
__global__ __launch_bounds__(256) void k_place(const int* __restrict__ src,
        const int* __restrict__ dst, const int* __restrict__ rank,
        const int* __restrict__ row_ptr, int* __restrict__ col_src, int E) {
  int e = blockIdx.x * 256 + threadIdx.x;
  if (e >= E) return;
  col_src[row_ptr[dst[e]] + rank[e]] = src[e];
}

// ============ one-time converts (merged: blocks 0..5 = W, rest = x) ========
__global__ __launch_bounds__(256) void k_cvt(const float* __restrict__ x,
        const float* __restrict__ Wl, const float* __restrict__ Wr,
        unsigned short* __restrict__ xb, unsigned short* __restrict__ wt,
        int total8) {
  if (blockIdx.x < 6) {
    int ls = blockIdx.x;           // layer*2 + side
    int l = ls >> 1, s = ls & 1;
    const float* W = (s ? Wr : Wl) + l * D * D;
    unsigned short* o = wt + ls * D * D;
    for (int it = 0; it < 64; ++it) {
      int idx = it * 256 + threadIdx.x;
      int k = idx >> 7, c = idx & 127;
      o[c * D + k] = f2bf(W[idx]);   // transposed, K-contiguous
    }
  } else {
    int i = (blockIdx.x - 6) * 256 + threadIdx.x;
    if (i >= total8) return;
    float4 a = ((const float4*)x)[2 * i];
    float4 b = ((const float4*)x)[2 * i + 1];
    uint4 pk;
    pk.x = (unsigned)f2bf(a.x) | ((unsigned)f2bf(a.y) << 16);
    pk.y = (unsigned)f2bf(a.z) | ((unsigned)f2bf(a.w) << 16);
    pk.z = (unsigned)f2bf(b.x) | ((unsigned)f2bf(b.y) << 16);
    pk.w = (unsigned)f2bf(b.z) | ((unsigned)f2bf(b.w) << 16);
    ((uint4*)xb)[i] = pk;
  }
}

// ============ GEMM: bf16 MFMA 16x16x32 =====================================
// Block (0,0) additionally zeroes sums64 for this layer's BN accumulation
// (runs strictly before k_agg's atomics via stream order).
__global__ __launch_bounds__(256) void k_gemm(const unsigned short* __restrict__ xb,
        const unsigned short* __restrict__ wt,   // this layer: [2][128 col][128 k]
        unsigned short* __restrict__ xlb, unsigned short* __restrict__ xrb,
        float* __restrict__ sums64, int n) {
  __shared__ unsigned short xs[128 * 128];   // 32 KB
  const int t = threadIdx.x;
  const int row0 = blockIdx.x * 128;
  const unsigned short* __restrict__ W = wt + (size_t)blockIdx.y * (D * D);
  unsigned short* __restrict__ outp = blockIdx.y ? xrb : xlb;

  if (blockIdx.x == 0 && blockIdx.y == 0) {
#pragma unroll
    for (int i = 0; i < SUM_SLOTS; ++i) sums64[i * 256 + t] = 0.f;
  }

#pragma unroll
  for (int i = 0; i < 8; ++i) {
    int ci = i * 256 + t;          // 16B-chunk index 0..2047
    int lr = ci >> 4, p = ci & 15;
    int grow = row0 + lr;
    if (grow >= n) grow = n - 1;   // clamped rows are never stored
    int gp = p ^ (lr & 7);
    uint4 v = *(const uint4*)(xb + (size_t)grow * D + gp * 8);
    *(uint4*)((char*)xs + ci * 16) = v;
  }
  __syncthreads();

  const int lane = t & 63, wv = t >> 6;
  const int colg = lane & 15, kg = lane >> 4;

  f32x4 acc[2][8];
#pragma unroll
  for (int rr = 0; rr < 2; ++rr)
#pragma unroll
    for (int cc = 0; cc < 8; ++cc) acc[rr][cc] = (f32x4)(0.f);

#pragma unroll
  for (int ks = 0; ks < 4; ++ks) {
    bf16x8 a[2], b[8];
#pragma unroll
    for (int rr = 0; rr < 2; ++rr) {
      int lr = wv * 32 + rr * 16 + colg;
      int byte = (lr * 256 + ks * 64 + kg * 16) ^ ((lr & 7) << 4);
      a[rr] = *(const bf16x8*)((const char*)xs + byte);
    }
#pragma unroll
    for (int cc = 0; cc < 8; ++cc) {
      int col = cc * 16 + colg;
      b[cc] = *(const bf16x8*)(W + (size_t)col * D + ks * 32 + kg * 8);
    }
#pragma unroll
    for (int rr = 0; rr < 2; ++rr)
#pragma unroll
      for (int cc = 0; cc < 8; ++cc)
        acc[rr][cc] = __builtin_amdgcn_mfma_f32_16x16x32_bf16(a[rr], b[cc], acc[rr][cc], 0, 0, 0);
  }

#pragma unroll
  for (int rr = 0; rr < 2; ++rr) {
    int rbase = row0 + wv * 32 + rr * 16 + kg * 4;
#pragma unroll
    for (int cc = 0; cc < 8; ++cc) {
      int col = cc * 16 + colg;
      f32x4 v = acc[rr][cc];
#pragma unroll
      for (int r = 0; r < 4; ++r) {
        int grow = rbase + r;
        if (grow < n) outp[(size_t)grow * D + col] = f2bf(v[r]);
      }
    }
  }
}

// ============ fused score + online-softmax + aggregate + BN partials =======
// 16 lanes per node (LPT order), batch-8 gather pipelining. Each block also
// LDS-reduces its 16 output rows' sum/sumsq and atomicAdds one 256-float
// partial into sums64[bid&63] (spread over 64 slots -> no hot-address chain).

__device__ __forceinline__ void agg_step(ushort8_t hv, const float* xrv,
        const float* atv, float& m, float& den, float* ac) {
  float v[8];
#pragma unroll
  for (int j = 0; j < 8; ++j) v[j] = bf2f(hv[j]);
  float p = 0.f;
#pragma unroll
  for (int j = 0; j < 8; ++j) {
    float tt = v[j] + xrv[j];
    tt = tt > 0.f ? tt : NEG_SLOPE * tt;
    p += tt * atv[j];
  }
  p += __shfl_xor(p, 1);
  p += __shfl_xor(p, 2);
  p += __shfl_xor(p, 4);
  p += __shfl_xor(p, 8);
  if (p > m) {
    float sc = __expf(m - p);
    den *= sc;
#pragma unroll
    for (int j = 0; j < 8; ++j) ac[j] *= sc;
    m = p;
  }
  float a = __expf(p - m);
  den += a;
#pragma unroll
  for (int j = 0; j < 8; ++j) ac[j] += a * v[j];
}

__global__ __launch_bounds__(256) void k_agg(const unsigned short* __restrict__ xlb,
        const unsigned short* __restrict__ xrb, const int* __restrict__ col_src,
        const int* __restrict__ row_ptr, const int* __restrict__ node_order,
        const float* __restrict__ att, float* __restrict__ out,
        float* __restrict__ sums64, int n) {
  __shared__ float lsum[16][128];
  __shared__ float lsq[16][128];
  int g = blockIdx.x * 16 + (threadIdx.x >> 4);
  int grp = threadIdx.x >> 4;
  int lane = threadIdx.x & 15;
  bool active = (g < n);          // 3125*16 == 50000: always true, kept for safety
  float r[8];
#pragma unroll
  for (int j = 0; j < 8; ++j) r[j] = 0.f;

  if (active) {
    int node = node_order[g];
    int ro = lane * 2;
    ushort8_t hr = ((const ushort8_t*)(xrb + (size_t)node * D))[lane];
    float xrv[8];
#pragma unroll
    for (int j = 0; j < 8; ++j) xrv[j] = bf2f(hr[j]);
    float4 at0 = ((const float4*)att)[ro];
    float4 at1 = ((const float4*)att)[ro + 1];
    float atv[8] = {at0.x, at0.y, at0.z, at0.w, at1.x, at1.y, at1.z, at1.w};

    int k0 = row_ptr[node], k1 = row_ptr[node + 1];
    float m = -1e30f, den = 0.f;
    float ac[8];
#pragma unroll
    for (int j = 0; j < 8; ++j) ac[j] = 0.f;

    const ushort8_t* xl8 = (const ushort8_t*)xlb;
    int k = k0;
    for (; k + 8 <= k1; k += 8) {
      int s0 = col_src[k],     s1 = col_src[k + 1], s2 = col_src[k + 2], s3 = col_src[k + 3];
      int s4 = col_src[k + 4], s5 = col_src[k + 5], s6 = col_src[k + 6], s7 = col_src[k + 7];
      ushort8_t h0 = xl8[(size_t)s0 * 16 + lane];
      ushort8_t h1 = xl8[(size_t)s1 * 16 + lane];
      ushort8_t h2 = xl8[(size_t)s2 * 16 + lane];
      ushort8_t h3 = xl8[(size_t)s3 * 16 + lane];
      ushort8_t h4 = xl8[(size_t)s4 * 16 + lane];
      ushort8_t h5 = xl8[(size_t)s5 * 16 + lane];
      ushort8_t h6 = xl8[(size_t)s6 * 16 + lane];
      ushort8_t h7 = xl8[(size_t)s7 * 16 + lane];
      agg_step(h0, xrv, atv, m, den, ac);
      agg_step(h1, xrv, atv, m, den, ac);
      agg_step(h2, xrv, atv, m, den, ac);
      agg_step(h3, xrv, atv, m, den, ac);
      agg_step(h4, xrv, atv, m, den, ac);
      agg_step(h5, xrv, atv, m, den, ac);
      agg_step(h6, xrv, atv, m, den, ac);
      agg_step(h7, xrv, atv, m, den, ac);
    }
    if (k + 4 <= k1) {
      int s0 = col_src[k], s1 = col_src[k + 1], s2 = col_src[k + 2], s3 = col_src[k + 3];
      ushort8_t h0 = xl8[(size_t)s0 * 16 + lane];
      ushort8_t h1 = xl8[(size_t)s1 * 16 + lane];
      ushort8_t h2 = xl8[(size_t)s2 * 16 + lane];
      ushort8_t h3 = xl8[(size_t)s3 * 16 + lane];
      agg_step(h0, xrv, atv, m, den, ac);
      agg_step(h1, xrv, atv, m, den, ac);
      agg_step(h2, xrv, atv, m, den, ac);
      agg_step(h3, xrv, atv, m, den, ac);
      k += 4;
    }
    for (; k < k1; ++k) {
      int s = col_src[k];
      ushort8_t h = xl8[(size_t)s * 16 + lane];
      agg_step(h, xrv, atv, m, den, ac);
    }

    float inv = 1.f / (den + 1e-16f);
#pragma unroll
    for (int j = 0; j < 8; ++j) r[j] = ac[j] * inv;
    float4* o4 = (float4*)out;
    o4[(size_t)node * 32 + ro]     = make_float4(r[0], r[1], r[2], r[3]);
    o4[(size_t)node * 32 + ro + 1] = make_float4(r[4], r[5], r[6], r[7]);
  }

  // ---- BN partials: LDS reduce 16 rows, one atomic record per block ----
#pragma unroll
  for (int j = 0; j < 8; ++j) {
    lsum[grp][lane * 8 + j] = r[j];
    lsq[grp][lane * 8 + j] = r[j] * r[j];
  }
  __syncthreads();
  int t = threadIdx.x;
  float s = 0.f;
  if (t < 128) {
#pragma unroll
    for (int gg = 0; gg < 16; ++gg) s += lsum[gg][t];
  } else {
#pragma unroll
    for (int gg = 0; gg < 16; ++gg) s += lsq[gg][t - 128];
  }
  atomicAdd(&sums64[(blockIdx.x & (SUM_SLOTS - 1)) * 256 + t], s);
}

// ============ BatchNorm finalize + apply ===================================
// Reduce the 64 slot-records (64KB), emit scale/shift.
__global__ void k_bn_fin2(const float* __restrict__ sums64,
        const float* __restrict__ gamma, const float* __restrict__ beta,
        float* __restrict__ ss, float inv_n) {
  __shared__ float tot[256];
  int t = threadIdx.x;
  float a0 = 0.f, a1 = 0.f, a2 = 0.f, a3 = 0.f;
#pragma unroll
  for (int k = 0; k < SUM_SLOTS; k += 4) {
    a0 += sums64[(k + 0) * 256 + t];
    a1 += sums64[(k + 1) * 256 + t];
    a2 += sums64[(k + 2) * 256 + t];
    a3 += sums64[(k + 3) * 256 + t];
  }
  tot[t] = (a0 + a1) + (a2 + a3);
  __syncthreads();
  if (t < 128) {
    float mu = tot[t] * inv_n;
    float var = tot[128 + t] * inv_n - mu * mu;
    float rs = rsqrtf(var + BN_EPS);
    float sc = gamma[t] * rs;
    ss[t] = sc;
    ss[128 + t] = beta[t] - mu * sc;
  }
}

// Normalize+GELU. Layers 0/1: write only bf16 xb (f32 out never read again);
// layer 2: write only f32 out (final output).
__global__ __launch_bounds__(256) void k_bn_apply(const float* __restrict__ agg,
        const float* __restrict__ ss, float* __restrict__ xo,
        unsigned short* __restrict__ xbo, int total4, int last) {
  int i = blockIdx.x * 256 + threadIdx.x;
  if (i >= total4) return;
  float4 v = ((const float4*)agg)[i];
  int c4 = i & (D / 4 - 1);
  float4 sc = ((const float4*)ss)[c4];
  float4 sh = ((const float4*)ss)[D / 4 + c4];
  float y0 = sc.x * v.x + sh.x;
  float y1 = sc.y * v.y + sh.y;
  float y2 = sc.z * v.z + sh.z;
  float y3 = sc.w * v.w + sh.w;
  float4 g;
  g.x = 0.5f * y0 * (1.f + erff(y0 * 0.70710678118654752f));
  g.y = 0.5f * y1 * (1.f + erff(y1 * 0.70710678118654752f));
  g.z = 0.5f * y2 * (1.f + erff(y2 * 0.70710678118654752f));
  g.w = 0.5f * y3 * (1.f + erff(y3 * 0.70710678118654752f));
  if (last) {
    ((float4*)xo)[i] = g;
  } else {
    uint2 pk;
    pk.x = (unsigned)f2bf(g.x) | ((unsigned)f2bf(g.y) << 16);
    pk.y = (unsigned)f2bf(g.z) | ((unsigned)f2bf(g.w) << 16);
    ((uint2*)xbo)[i] = pk;
  }
}

// ===========================================================================

extern "C" void kernel_launch(void* const* d_in, const int* in_sizes, int n_in,
                              void* d_out, int out_size, void* d_ws, size_t ws_size,
                              hipStream_t stream) {
  const float* x0    = (const float*)d_in[0];
  const int*   ei    = (const int*)d_in[1];
  const float* Wl    = (const float*)d_in[2];
  const float* Wr    = (const float*)d_in[3];
  const float* att   = (const float*)d_in[4];
  // d_in[5] = bias: cancelled exactly by BatchNorm mean-subtraction; unused.
  const float* gamma = (const float*)d_in[6];
  const float* beta  = (const float*)d_in[7];
  float* out = (float*)d_out;

  float* ws = (float*)d_ws;
  unsigned short* xb  = (unsigned short*)ws;              // [N][128] bf16
  unsigned short* xlb = (unsigned short*)(ws + 3200000);  // [N][128] bf16
  unsigned short* xrb = (unsigned short*)(ws + 6400000);  // [N][128] bf16
  int*   col_src    = (int*)(ws + 9600000);       //   800,000
  int*   rank       = (int*)(ws + 10400000);      //   800,000
  int*   row_ptr    = (int*)(ws + 11200000);      //    50,001
  int*   counts     = (int*)(ws + 11250004);      // COUNTS_PAD (53,248)
  int*   node_order = (int*)(ws + 11303252);      //    50,000
  float* sums64     = ws + 11353252;              //    16,384 (64 x 256)
  float* ss         = ws + 11369636;              //       256
  unsigned short* wt = (unsigned short*)(ws + 11369892);  // [3][2][128][128] bf16

  const int* src = ei;
  const int* dst = ei + NEDGES;

  // ---- one-time: CSR build + LPT sort + converts (5 dispatches) ----
  hipMemsetAsync(counts, 0, COUNTS_PAD * sizeof(int), stream);
  k_rank<<<(NEDGES + 255) / 256, 256, 0, stream>>>(dst, counts, rank, NEDGES);
  k_scan_sort<<<1, SCAN_THREADS, 0, stream>>>(counts, row_ptr, node_order, NNODES);
  k_place<<<(NEDGES + 255) / 256, 256, 0, stream>>>(src, dst, rank, row_ptr, col_src, NEDGES);
  k_cvt<<<6 + (NNODES * (D / 8) + 255) / 256, 256, 0, stream>>>(x0, Wl, Wr, xb, wt,
                                                                NNODES * (D / 8));

  dim3 ggrid((NNODES + 127) / 128, 2);

  for (int l = 0; l < 3; ++l) {
    k_gemm<<<ggrid, 256, 0, stream>>>(xb, wt + (size_t)l * 2 * D * D, xlb, xrb,
                                      sums64, NNODES);

    // d_out is dead as an input after k_gemm -> safe to overwrite with agg.
    k_agg<<<(NNODES + 15) / 16, 256, 0, stream>>>(xlb, xrb, col_src, row_ptr,
                                                  node_order, att + l * D, out,
                                                  sums64, NNODES);

    k_bn_fin2<<<1, 256, 0, stream>>>(sums64, gamma + l * D, beta + l * D, ss, 1.0f / NNODES);
    k_bn_apply<<<(NNODES * (D / 4) + 255) / 256, 256, 0, stream>>>(out, ss, out, xb,
                                                                   NNODES * (D / 4),
                                                                   l == 2 ? 1 : 0);
  }
}